// Round 7
// baseline (6623.255 us; speedup 1.0000x reference)
//
#include <hip/hip_runtime.h>
#include <math.h>

// ---------------- constants ----------------
#define NTOK 30464    // 448*68 = 238 tiles of 128
#define NEMB 28672    // 448*64
typedef unsigned short ushort;
typedef __attribute__((ext_vector_type(8))) __bf16 bf16x8_t;
typedef __attribute__((ext_vector_type(4))) float f32x4_t;

#if defined(__has_builtin)
#if __has_builtin(__builtin_amdgcn_global_load_lds)
#define HAS_GLL 1
#endif
#endif

// ---------------- helpers ----------------
__device__ __forceinline__ ushort f2bf(float f) {
  unsigned int u = __float_as_uint(f);
  u += 0x7fffu + ((u >> 16) & 1u);   // RNE (finite inputs)
  return (ushort)(u >> 16);
}
__device__ __forceinline__ float bf2f(ushort u) {
  return __uint_as_float(((unsigned int)u) << 16);
}

#ifdef HAS_GLL
__device__ __forceinline__ void gll16(const ushort* g, ushort* l) {
  __builtin_amdgcn_global_load_lds(
      (const __attribute__((address_space(1))) unsigned int*)g,
      (__attribute__((address_space(3))) unsigned int*)l, 16, 0, 0);
}
#endif

__device__ __forceinline__ float block_reduce_sum(float v, float* scratch) {
  __syncthreads();
  #pragma unroll
  for (int o = 32; o; o >>= 1) v += __shfl_xor(v, o, 64);
  int wid = threadIdx.x >> 6, lane = threadIdx.x & 63;
  if (lane == 0) scratch[wid] = v;
  __syncthreads();
  if (threadIdx.x == 0) {
    float s = 0.f;
    int nw = (blockDim.x + 63) >> 6;
    for (int i = 0; i < nw; i++) s += scratch[i];
    scratch[0] = s;
  }
  __syncthreads();
  return scratch[0];
}

// exact tanh-gelu via sigmoid identity: 0.5x(1+tanh(z)) = x / (1 + e^{-2z})
__device__ __forceinline__ float gelu_f(float x) {
  float z2 = 1.5957691216057308f * (x + 0.044715f * x * x * x);
  return x / (1.0f + __expf(-z2));
}

// ---------------- RevIN ----------------
__global__ __launch_bounds__(256) void revin_kernel(const float* __restrict__ x,
    float* __restrict__ xr, float* __restrict__ means, float* __restrict__ stdev) {
  int bm = blockIdx.x;
  int b = bm / 7, m = bm % 7;
  int tid = threadIdx.x;
  __shared__ float red[8];
  float v0 = x[(size_t)b * 3584 + (size_t)tid * 7 + m];
  float v1 = x[(size_t)b * 3584 + (size_t)(tid + 256) * 7 + m];
  float s  = block_reduce_sum(v0 + v1, red);
  float ss = block_reduce_sum(v0 * v0 + v1 * v1, red);
  float mean = s * (1.0f / 512.0f);
  float var  = ss * (1.0f / 512.0f) - mean * mean;
  float sd = sqrtf(var + 1e-5f);
  if (tid == 0) { means[bm] = mean; stdev[bm] = sd; }
  float inv = 1.0f / sd;
  xr[(size_t)bm * 512 + tid]       = (v0 - mean) * inv;
  xr[(size_t)bm * 512 + tid + 256] = (v1 - mean) * inv;
}

// ---------------- decompose ----------------
__global__ __launch_bounds__(256) void decompose_kernel(const float* __restrict__ xr,
    float* __restrict__ dec) {
  int n = blockIdx.x, tid = threadIdx.x;
  __shared__ float xv[512];
  __shared__ float tr[512];
  __shared__ float sumS[24];
  for (int l = tid; l < 512; l += 256) xv[l] = xr[(size_t)n * 512 + l];
  if (tid < 24) sumS[tid] = 0.f;
  __syncthreads();
  for (int l = tid; l < 512; l += 256) {
    int t0 = l - 12; t0 = t0 < 0 ? 0 : (t0 > 488 ? 488 : t0);
    float s = 0.f;
    #pragma unroll
    for (int j = 0; j < 24; j++) s += xv[t0 + j];
    float t = s * (1.0f / 24.0f);
    tr[l] = t;
    atomicAdd(&sumS[l % 24], xv[l] - t);
  }
  __syncthreads();
  if (tid < 24) sumS[tid] *= (tid < 8) ? (1.0f / 22.0f) : (1.0f / 21.0f);
  __syncthreads();
  float* dp = dec + (size_t)n * 1536;
  for (int l = tid; l < 512; l += 256) {
    float t = tr[l], se = sumS[l % 24];
    dp[l] = t;
    dp[512 + l] = se;
    dp[1024 + l] = xv[l] - t - se;
  }
}

// ---------------- patch + embed -> h rows 4..67 (NO wpe yet) ----------------
__global__ __launch_bounds__(256) void embed_kernel(const float* __restrict__ dec,
    const float* __restrict__ in_w, const float* __restrict__ in_b, float* __restrict__ h) {
  int blk = blockIdx.x;            // 448 * 4
  int n = blk >> 2, pg = blk & 3;  // series, patch-group of 16
  int tid = threadIdx.x;
  __shared__ __align__(16) float tok[16][48];
  for (int idx = tid; idx < 768; idx += 256) {
    int p = idx / 48, k = idx - p * 48;
    int c = k >> 4, j = k & 15;
    int l = (pg * 16 + p) * 8 + j; if (l > 511) l = 511;
    tok[p][k] = dec[(size_t)n * 1536 + (size_t)c * 512 + l];
  }
  __syncthreads();
  const int d0 = tid, d1 = tid + 256, d2 = tid + 512;
  float acc[16][3];
  float b0 = in_b[d0], b1 = in_b[d1], b2 = in_b[d2];
  #pragma unroll
  for (int p = 0; p < 16; p++) { acc[p][0] = b0; acc[p][1] = b1; acc[p][2] = b2; }
  for (int kq = 0; kq < 12; kq++) {
    float w0[4], w1[4], w2[4];
    #pragma unroll
    for (int kk = 0; kk < 4; kk++) {
      const float* wp = in_w + (size_t)(kq * 4 + kk) * 768;
      w0[kk] = wp[d0]; w1[kk] = wp[d1]; w2[kk] = wp[d2];
    }
    #pragma unroll
    for (int p = 0; p < 16; p++) {
      float4 t = *(const float4*)&tok[p][kq * 4];
      acc[p][0] += t.x * w0[0]; acc[p][1] += t.x * w1[0]; acc[p][2] += t.x * w2[0];
      acc[p][0] += t.y * w0[1]; acc[p][1] += t.y * w1[1]; acc[p][2] += t.y * w2[1];
      acc[p][0] += t.z * w0[2]; acc[p][1] += t.z * w1[2]; acc[p][2] += t.z * w2[2];
      acc[p][0] += t.w * w0[3]; acc[p][1] += t.w * w1[3]; acc[p][2] += t.w * w2[3];
    }
  }
  #pragma unroll
  for (int p = 0; p < 16; p++) {
    float* outp = h + ((size_t)n * 68 + 4 + pg * 16 + p) * 768;
    outp[d0] = acc[p][0]; outp[d1] = acc[p][1]; outp[d2] = acc[p][2];
  }
}

// ---------------- key normalization ----------------
__global__ __launch_bounds__(256) void keyn_kernel(const float* __restrict__ pkey,
    float* __restrict__ keyn, double* __restrict__ kinv) {
  int k = blockIdx.x, tid = threadIdx.x;
  __shared__ double redd[4];
  float v[3];
  double ss = 0.0;
  #pragma unroll
  for (int i = 0; i < 3; i++) {
    v[i] = pkey[(size_t)k * 768 + tid + i * 256];
    ss += (double)v[i] * (double)v[i];
  }
  #pragma unroll
  for (int o = 32; o; o >>= 1) ss += __shfl_xor(ss, o, 64);
  int wid = tid >> 6, lane = tid & 63;
  if (lane == 0) redd[wid] = ss;
  __syncthreads();
  if (tid == 0) redd[0] = redd[0] + redd[1] + redd[2] + redd[3];
  __syncthreads();
  ss = redd[0];
  double inv = 1.0 / sqrt(ss > 1e-12 ? ss : 1e-12);
  #pragma unroll
  for (int i = 0; i < 3; i++)
    keyn[(size_t)k * 768 + tid + i * 256] = (float)((double)v[i] * inv);
  if (tid == 0) kinv[k] = inv;
}

// ---------------- xq ----------------
__global__ __launch_bounds__(256) void xq_kernel(const float* __restrict__ h,
    float* __restrict__ xq) {
  int n = blockIdx.x, tid = threadIdx.x;
  __shared__ float red[8];
  float vals[3];
  float ssl = 0.f;
  #pragma unroll
  for (int i = 0; i < 3; i++) {
    int d = tid + i * 256;
    const float* p = h + ((size_t)n * 68 + 4) * 768 + d;
    float s = 0.f;
    for (int pc = 0; pc < 64; pc++) s += p[(size_t)pc * 768];
    s *= (1.0f / 64.0f);
    vals[i] = s; ssl += s * s;
  }
  float ss = block_reduce_sum(ssl, red);
  float inv = rsqrtf(fmaxf(ss, 1e-12f));
  #pragma unroll
  for (int i = 0; i < 3; i++)
    xq[(size_t)n * 768 + tid + i * 256] = vals[i] * inv;
}

__global__ void zero_kernel(float* p) {
  if (threadIdx.x == 0 && blockIdx.x == 0) p[0] = 0.f;
}

// ---------------- sim matrix (f64, high-parallelism) ----------------
__global__ __launch_bounds__(256) void sim_kernel(
    const float* __restrict__ xq, const float* __restrict__ pkey,
    const double* __restrict__ kinv, double* __restrict__ simd) {
  int n = blockIdx.y;
  int kbase = blockIdx.x * 128;
  int tid = threadIdx.x;
  __shared__ __align__(16) float xqv[768];
  #pragma unroll
  for (int i = 0; i < 3; i++) xqv[tid + i * 256] = xq[(size_t)n * 768 + tid + i * 256];
  __syncthreads();
  int lane = tid & 63, wid = tid >> 6;
  double xd[12];
  #pragma unroll
  for (int i = 0; i < 12; i++) xd[i] = (double)xqv[lane * 12 + i];

  for (int k4 = kbase + wid * 4; k4 < kbase + 128; k4 += 16) {
    int kt[4];
    #pragma unroll
    for (int t = 0; t < 4; t++) { int k = k4 + t; kt[t] = k < 1000 ? k : 999; }
    float4 v[4][3];
    #pragma unroll
    for (int t = 0; t < 4; t++)
      #pragma unroll
      for (int j = 0; j < 3; j++)
        v[t][j] = *(const float4*)(pkey + (size_t)kt[t] * 768 + lane * 12 + j * 4);
    double a[4] = {0.0, 0.0, 0.0, 0.0};
    #pragma unroll
    for (int t = 0; t < 4; t++)
      #pragma unroll
      for (int j = 0; j < 3; j++) {
        a[t] += (double)v[t][j].x * xd[4 * j + 0];
        a[t] += (double)v[t][j].y * xd[4 * j + 1];
        a[t] += (double)v[t][j].z * xd[4 * j + 2];
        a[t] += (double)v[t][j].w * xd[4 * j + 3];
      }
    #pragma unroll
    for (int t = 0; t < 4; t++)
      #pragma unroll
      for (int o = 32; o; o >>= 1) a[t] += __shfl_xor(a[t], o, 64);
    if (lane == 0) {
      #pragma unroll
      for (int t = 0; t < 4; t++) {
        int k = k4 + t;
        if (k < 1000) simd[(size_t)n * 1000 + k] = a[t] * kinv[k];
      }
    }
  }
}

// ---------------- top-4 + prompt rows + reduce_sim ----------------
__global__ __launch_bounds__(256) void topk_kernel(
    const float* __restrict__ xq, const double* __restrict__ simd_g,
    const float* __restrict__ keyn, const float* __restrict__ wpe,
    float* __restrict__ h, float* __restrict__ rs_out) {
  int n = blockIdx.x, tid = threadIdx.x;
  __shared__ __align__(16) float xqv[768];
  __shared__ double simd_s[1000];
  __shared__ int idxs[4];
  __shared__ double redv[4];
  __shared__ int redi[4];
  __shared__ float red2[8];
  #pragma unroll
  for (int i = 0; i < 3; i++) xqv[tid + i * 256] = xq[(size_t)n * 768 + tid + i * 256];
  for (int k = tid; k < 1000; k += 256) simd_s[k] = simd_g[(size_t)n * 1000 + k];
  __syncthreads();
  int lane = tid & 63, wid = tid >> 6;
  for (int r = 0; r < 4; r++) {
    double bv = -1e300; int bi = 0x7fffffff;
    for (int k = tid; k < 1000; k += 256) {
      double v = simd_s[k];
      if (v > bv || (v == bv && k < bi)) { bv = v; bi = k; }
    }
    #pragma unroll
    for (int off = 32; off; off >>= 1) {
      double ov = __shfl_xor(bv, off, 64);
      int oi = __shfl_xor(bi, off, 64);
      if (ov > bv || (ov == bv && oi < bi)) { bv = ov; bi = oi; }
    }
    if (lane == 0) { redv[wid] = bv; redi[wid] = bi; }
    __syncthreads();
    if (tid == 0) {
      double fv = redv[0]; int fi = redi[0];
      for (int w = 1; w < 4; w++)
        if (redv[w] > fv || (redv[w] == fv && redi[w] < fi)) { fv = redv[w]; fi = redi[w]; }
      idxs[r] = fi; simd_s[fi] = -1e300;
    }
    __syncthreads();
  }
  float part = 0.f;
  for (int r = 0; r < 4; r++) {
    int ki = idxs[r];
    const float* kp = keyn + (size_t)ki * 768;
    const float* wp = wpe + (size_t)r * 768;
    float* hp = h + ((size_t)n * 68 + r) * 768;
    #pragma unroll
    for (int i = 0; i < 3; i++) {
      int d = tid + i * 256;
      float kv = kp[d];
      hp[d] = kv + wp[d];
      part += kv * xqv[d];
    }
  }
  part = block_reduce_sum(part, red2);
  if (tid == 0) atomicAdd(rs_out, part * (1.0f / 448.0f));
}

// ---------------- h rows 4..67 += wpe ----------------
__global__ __launch_bounds__(256) void addwpe_kernel(const float* __restrict__ wpe,
    float* __restrict__ h) {
  int np = blockIdx.x;
  int n = np >> 6, p = np & 63;
  int tid = threadIdx.x;
  const float* wp = wpe + (size_t)(4 + p) * 768;
  float* hp = h + ((size_t)n * 68 + 4 + p) * 768;
  #pragma unroll
  for (int i = 0; i < 3; i++) { int d = tid + i * 256; hp[d] += wp[d]; }
}

// ---------------- LayerNorm -> bf16 ----------------
__global__ __launch_bounds__(256) void ln_kernel(const float* __restrict__ src,
    ushort* __restrict__ dst, const float* __restrict__ g, const float* __restrict__ b) {
  size_t row = blockIdx.x;
  const float* xp = src + row * 768;
  ushort* yp = dst + row * 768;
  int tid = threadIdx.x;
  float v0 = xp[tid], v1 = xp[tid + 256], v2 = xp[tid + 512];
  __shared__ float red[8];
  float s  = block_reduce_sum(v0 + v1 + v2, red);
  float ss = block_reduce_sum(v0 * v0 + v1 * v1 + v2 * v2, red);
  float mean = s * (1.0f / 768.0f);
  float var  = ss * (1.0f / 768.0f) - mean * mean;
  float rs = rsqrtf(var + 1e-5f);
  yp[tid]       = f2bf((v0 - mean) * rs * g[tid]       + b[tid]);
  yp[tid + 256] = f2bf((v1 - mean) * rs * g[tid + 256] + b[tid + 256]);
  yp[tid + 512] = f2bf((v2 - mean) * rs * g[tid + 512] + b[tid + 512]);
}

// ---------------- cast+transpose weights: W[K][N] f32 -> WT[N][K] bf16 ----------------
__global__ __launch_bounds__(256) void tcast_kernel(const float* __restrict__ W,
    ushort* __restrict__ WT, int K, int N) {
  __shared__ ushort t[32][33];
  int n0 = blockIdx.x * 32, k0 = blockIdx.y * 32;
  int tx = threadIdx.x & 31, ty = threadIdx.x >> 5;   // 32 x 8
  #pragma unroll
  for (int i = 0; i < 4; i++) {
    int kk = ty + i * 8;
    t[kk][tx] = f2bf(W[(size_t)(k0 + kk) * N + n0 + tx]);
  }
  __syncthreads();
  #pragma unroll
  for (int i = 0; i < 4; i++) {
    int nn = ty + i * 8;
    WT[(size_t)(n0 + nn) * K + k0 + tx] = t[tx][nn];
  }
}

// ---------------- bf16 MFMA GEMM (m97-style global_load_lds staging) ----------------
// C = A(MxK) @ WT(NxK)^T + bias. 128x128 tile, 4 waves, 16x16x32 bf16.
// mode 0: C bf16;  1: C bf16 w/ gelu;  2: C fp32 += (residual)
__global__ __launch_bounds__(256) void mfma_gemm(const ushort* __restrict__ A,
    const ushort* __restrict__ WT, const float* __restrict__ bias, void* __restrict__ Cp,
    int M, int N, int K, int mode) {
  __shared__ ushort As[128 * 32];
  __shared__ ushort Bs[128 * 32];
  const int tid = threadIdx.x;
  const int row0 = blockIdx.y * 128, col0 = blockIdx.x * 128;
  const int w = tid >> 6, lane = tid & 63;
  const int wm = w >> 1, wn = w & 1;
  const int lm = lane & 15, quad = lane >> 4;
  const int srow = w * 16 + (lane >> 2);
  const int scol = (lane & 3) * 8;
  const ushort* agp0 = A  + (size_t)(row0 + srow)      * K + scol;
  const ushort* agp1 = A  + (size_t)(row0 + 64 + srow) * K + scol;
  const ushort* bgp0 = WT + (size_t)(col0 + srow)      * K + scol;
  const ushort* bgp1 = WT + (size_t)(col0 + 64 + srow) * K + scol;
  ushort* al0 = &As[w * 512];
  ushort* al1 = &As[2048 + w * 512];
  ushort* bl0 = &Bs[w * 512];
  ushort* bl1 = &Bs[2048 + w * 512];
  f32x4_t acc[4][4];
  #pragma unroll
  for (int mi = 0; mi < 4; mi++)
    #pragma unroll
    for (int ni = 0; ni < 4; ni++) acc[mi][ni] = (f32x4_t)(0.0f);

  for (int kb = 0; kb < K; kb += 32) {
    __syncthreads();
#ifdef HAS_GLL
    gll16(agp0 + kb, al0);
    gll16(agp1 + kb, al1);
    gll16(bgp0 + kb, bl0);
    gll16(bgp1 + kb, bl1);
#else
    {
      uint4 va0 = *(const uint4*)(agp0 + kb);
      uint4 va1 = *(const uint4*)(agp1 + kb);
      uint4 vb0 = *(const uint4*)(bgp0 + kb);
      uint4 vb1 = *(const uint4*)(bgp1 + kb);
      *(uint4*)&al0[lane * 8] = va0;
      *(uint4*)&al1[lane * 8] = va1;
      *(uint4*)&bl0[lane * 8] = vb0;
      *(uint4*)&bl1[lane * 8] = vb1;
    }
#endif
    __syncthreads();
    bf16x8_t af[4], bfr[4];
    #pragma unroll
    for (int mi = 0; mi < 4; mi++)
      af[mi] = *(const bf16x8_t*)&As[(wm * 64 + mi * 16 + lm) * 32 + quad * 8];
    #pragma unroll
    for (int ni = 0; ni < 4; ni++)
      bfr[ni] = *(const bf16x8_t*)&Bs[(wn * 64 + ni * 16 + lm) * 32 + quad * 8];
    #pragma unroll
    for (int mi = 0; mi < 4; mi++)
      #pragma unroll
      for (int ni = 0; ni < 4; ni++)
        acc[mi][ni] = __builtin_amdgcn_mfma_f32_16x16x32_bf16(af[mi], bfr[ni], acc[mi][ni], 0, 0, 0);
  }
  #pragma unroll
  for (int mi = 0; mi < 4; mi++) {
    #pragma unroll
    for (int ni = 0; ni < 4; ni++) {
      int gcol = col0 + wn * 64 + ni * 16 + lm;
      float bz = bias[gcol];
      #pragma unroll
      for (int r = 0; r < 4; r++) {
        int grow = row0 + wm * 64 + mi * 16 + quad * 4 + r;
        float v = acc[mi][ni][r] + bz;
        if (mode == 0)      ((ushort*)Cp)[(size_t)grow * N + gcol] = f2bf(v);
        else if (mode == 1) ((ushort*)Cp)[(size_t)grow * N + gcol] = f2bf(gelu_f(v));
        else { float* c = (float*)Cp + (size_t)grow * N + gcol; *c += v; }
      }
    }
  }
}

// ---------------- MFMA attention: block = (series-in-chunk, head) ----------------
__global__ __launch_bounds__(256) void attn_kernel(const ushort* __restrict__ qkvc,
    ushort* __restrict__ obase) {
  __shared__ __align__(16) ushort qk[2 * 80 * 64];
  __shared__ __align__(16) ushort vt[64][96];
  __shared__ __align__(16) float  sS[68][80];
  ushort* qs = qk;
  ushort* ks = qk + 80 * 64;
  ushort (*P)[96] = (ushort(*)[96])qk;

  int nh = blockIdx.x;
  int nl = nh / 12, hh = nh % 12;
  int tid = threadIdx.x;
  const int w = tid >> 6, lane = tid & 63;
  const int lm = lane & 15, quad = lane >> 4;
  const ushort* base = qkvc + (size_t)nl * 68 * 2304 + hh * 64;

  // vectorized load: one uint4 (8 bf16) per matrix per chunk; 68 rows x 8 segs
  for (int idx = tid; idx < 68 * 8; idx += 256) {
    int t = idx >> 3, seg = (idx & 7) * 8;
    const ushort* rp = base + (size_t)t * 2304 + seg;
    uint4 q = *(const uint4*)(rp);
    uint4 k = *(const uint4*)(rp + 768);
    uint4 v = *(const uint4*)(rp + 1536);
    *(uint4*)&qs[t * 64 + seg] = q;
    *(uint4*)&ks[t * 64 + seg] = k;
    const ushort* pv = (const ushort*)&v;
    #pragma unroll
    for (int j = 0; j < 8; j++) vt[seg + j][t] = pv[j];
  }
  for (int idx = tid; idx < 64 * 28; idx += 256) {
    int d = idx / 28, t = 68 + idx % 28;
    vt[d][t] = 0;
  }
  __syncthreads();

  for (int t5 = w; t5 < 25; t5 += 4) {
    int mi = t5 / 5, ni = t5 % 5;
    bf16x8_t a0 = *(const bf16x8_t*)&qs[(mi * 16 + lm) * 64 + quad * 8];
    bf16x8_t a1 = *(const bf16x8_t*)&qs[(mi * 16 + lm) * 64 + 32 + quad * 8];
    bf16x8_t b0 = *(const bf16x8_t*)&ks[(ni * 16 + lm) * 64 + quad * 8];
    bf16x8_t b1 = *(const bf16x8_t*)&ks[(ni * 16 + lm) * 64 + 32 + quad * 8];
    f32x4_t acc = (f32x4_t)(0.0f);
    acc = __builtin_amdgcn_mfma_f32_16x16x32_bf16(a0, b0, acc, 0, 0, 0);
    acc = __builtin_amdgcn_mfma_f32_16x16x32_bf16(a1, b1, acc, 0, 0, 0);
    int col = ni * 16 + lm;
    #pragma unroll
    for (int r = 0; r < 4; r++) {
      int row = mi * 16 + quad * 4 + r;
      if (row < 68) {
        float sv = (col > row || col >= 68) ? -1e9f : acc[r] * 0.125f;
        sS[row][col] = sv;
      }
    }
  }
  __syncthreads();

  // wave-parallel softmax: each 4-lane quad owns a row (q uniform per quad,
  // shfl_xor 1/2 stays inside the quad). Max is order-independent; sum is
  // reassociated (1-ulp class, inside tolerance).
  {
    int q = tid >> 2, lq = tid & 3;
    for (int r = q; r < 68; r += 64) {
      float mx = -1e30f;
      for (int c = lq; c < 80; c += 4) mx = fmaxf(mx, sS[r][c]);
      mx = fmaxf(mx, __shfl_xor(mx, 1, 64));
      mx = fmaxf(mx, __shfl_xor(mx, 2, 64));
      float s = 0.f;
      for (int c = lq; c < 80; c += 4) {
        float e = __expf(sS[r][c] - mx);
        sS[r][c] = e; s += e;
      }
      s += __shfl_xor(s, 1, 64);
      s += __shfl_xor(s, 2, 64);
      float inv = 1.0f / s;
      for (int c = lq; c < 80; c += 4) P[r][c] = f2bf(sS[r][c] * inv);
      for (int c = 80 + lq; c < 96; c += 4) P[r][c] = 0;
    }
    for (int idx = tid; idx < 12 * 96; idx += 256) {
      int r = 68 + idx / 96, c = idx % 96;
      P[r][c] = 0;
    }
  }
  __syncthreads();

  for (int t5 = w; t5 < 20; t5 += 4) {
    int mi = t5 % 5, ni = t5 / 5;
    f32x4_t acc = (f32x4_t)(0.0f);
    #pragma unroll
    for (int kk = 0; kk < 3; kk++) {
      bf16x8_t a = *(const bf16x8_t*)&P[mi * 16 + lm][kk * 32 + quad * 8];
      bf16x8_t b = *(const bf16x8_t*)&vt[ni * 16 + lm][kk * 32 + quad * 8];
      acc = __builtin_amdgcn_mfma_f32_16x16x32_bf16(a, b, acc, 0, 0, 0);
    }
    int col = ni * 16 + lm;
    #pragma unroll
    for (int r = 0; r < 4; r++) {
      int row = mi * 16 + quad * 4 + r;
      if (row < 68)
        obase[((size_t)nl * 68 + row) * 768 + hh * 64 + col] = f2bf(acc[r]);
    }
  }
}

// ---------------- final head ----------------
__global__ __launch_bounds__(256) void initof_kernel(const float* __restrict__ ob,
    float* __restrict__ of) {
  int i = blockIdx.x * 256 + threadIdx.x;
  of[i] = ob[i % 96];
}

// MFMA split-K head GEMM: of(1344x96) += A(1344x17408) @ WT(96x17408)^T
__global__ __launch_bounds__(256) void splitk_kernel(const ushort* __restrict__ A,
    const ushort* __restrict__ WT, float* __restrict__ of) {
  __shared__ ushort As[64 * 32];
  __shared__ ushort Ws[96 * 32];
  const int tid = threadIdx.x;
  const int row0 = blockIdx.x * 64;
  const int k0 = blockIdx.y * 1024;
  const int w = tid >> 6, lane = tid & 63;
  const int lm = lane & 15, quad = lane >> 4;
  const ushort* agp  = A  + (size_t)(row0 + (tid >> 2)) * 17408 + (tid & 3) * 8;
  const ushort* wgp1 = WT + (size_t)(tid >> 2) * 17408 + (tid & 3) * 8;
  const ushort* wgp2 = WT + (size_t)(64 + (tid >> 2)) * 17408 + (tid & 3) * 8;
  ushort* asl  = &As[w * 512];
  ushort* wsl1 = &Ws[w * 512];
  ushort* wsl2 = &Ws[2048 + w * 512];
  f32x4_t acc[6];
  #pragma unroll
  for (int ni = 0; ni < 6; ni++) acc[ni] = (f32x4_t)(0.0f);
  for (int kb = k0; kb < k0 + 1024; kb += 32) {
    __syncthreads();
#ifdef HAS_GLL
    gll16(agp + kb, asl);
    gll16(wgp1 + kb, wsl1);
    if (w < 2) gll16(wgp2 + kb, wsl2);
#else
    {
      uint4 va = *(const uint4*)(agp + kb);
      *(uint4*)&As[tid * 8] = va;
      uint4 vw = *(const uint4*)(wgp1 + kb);
      *(uint4*)&Ws[tid * 8] = vw;
      if (tid < 128) {
        uint4 vw2 = *(const uint4*)(wgp2 + kb);
        *(uint4*)&Ws[2048 + tid * 8] = vw2;
      }
    }
#endif
    __syncthreads();
    bf16x8_t af = *(const bf16x8_t*)&As[(w * 16 + lm) * 32 + quad * 8];
    #pragma unroll
    for (int ni = 0; ni < 6; ni++) {
      bf16x8_t bfrag = *(const bf16x8_t*)&Ws[(ni * 16 + lm) * 32 + quad * 8];
      acc[ni] = __builtin_amdgcn_mfma_f32_16x16x32_bf16(af, bfrag, acc[ni], 0, 0, 0);
    }
  }
  #pragma unroll
  for (int ni = 0; ni < 6; ni++) {
    int col = ni * 16 + lm;
    #pragma unroll
    for (int r = 0; r < 4; r++) {
      int grow = row0 + w * 16 + quad * 4 + r;
      atomicAdd(&of[(size_t)grow * 96 + col], acc[ni][r]);
    }
  }
}

__global__ void combine_kernel(const float* __restrict__ of, const float* __restrict__ stdev,
    const float* __restrict__ means, float* __restrict__ out) {
  int bm = blockIdx.x;
  int b = bm / 7, m = bm % 7;
  int j = threadIdx.x;
  if (j < 96) {
    float s = of[(size_t)(bm * 3 + 0) * 96 + j]
            + of[(size_t)(bm * 3 + 1) * 96 + j]
            + of[(size_t)(bm * 3 + 2) * 96 + j];
    out[(size_t)b * 672 + (size_t)j * 7 + m] = s * stdev[bm] + means[bm];
  }
}

// ---------------- launcher ----------------
extern "C" void kernel_launch(void* const* d_in, const int* in_sizes, int n_in,
                              void* d_out, int out_size, void* d_ws, size_t ws_size,
                              hipStream_t stream) {
  (void)in_sizes; (void)n_in; (void)out_size;
  const float* x     = (const float*)d_in[0];
  const float* in_w  = (const float*)d_in[2];
  const float* in_b  = (const float*)d_in[3];
  const float* pkey  = (const float*)d_in[4];
  const float* wpe   = (const float*)d_in[5];
  const float* ln1_g = (const float*)d_in[6];
  const float* ln1_b = (const float*)d_in[7];
  const float* qkv_w = (const float*)d_in[8];
  const float* qkv_b = (const float*)d_in[9];
  const float* aw    = (const float*)d_in[10];
  const float* ab    = (const float*)d_in[11];
  const float* ln2_g = (const float*)d_in[12];
  const float* ln2_b = (const float*)d_in[13];
  const float* fc_w  = (const float*)d_in[14];
  const float* fc_b  = (const float*)d_in[15];
  const float* mp_w  = (const float*)d_in[16];
  const float* mp_b  = (const float*)d_in[17];
  const float* lnf_g = (const float*)d_in[18];
  const float* lnf_b = (const float*)d_in[19];
  const float* out_w = (const float*)d_in[20];
  const float* out_b = (const float*)d_in[21];
  float* out = (float*)d_out;
  float* ws  = (float*)d_ws;

  // workspace layout: small (2,161,664 f) + h + abuf16 + w16 + scr (rest)
  float* means = ws;
  float* stdev = ws + 512;
  float* xr    = ws + 1024;
  float* dec   = xr + 229376;
  float* keyn  = dec + 688128;
  double* kinv = (double*)(keyn + 768000);
  float* xq    = keyn + 768000 + 2048;
  float* of    = xq + 344064;
  float* h     = of + 129024;                 // 23,396,352 f
  ushort* abuf16 = (ushort*)(h + 23396352);   // 23,396,352 us
  ushort* w16    = abuf16 + 23396352;         // 7,077,888 us
  ushort* scr16  = w16 + 7077888;             // remainder
  ushort* owT16  = scr16;                     // alias (only used after layers)

  // sim matrix (448 x 1000 f64 = 3.584 MB) reuses the xr+dec region
  // (3.67 MB, dead after embed_kernel; 8B-aligned: ws+4096 bytes)
  double* simd = (double*)xr;

  ushort* wqT  = w16;                         // 2304 x 768
  ushort* waT  = wqT + 2304 * 768;            // 768 x 768
  ushort* wfcT = waT + 768 * 768;             // 3072 x 768
  ushort* wmpT = wfcT + 3072 * 768;           // 768 x 3072

  // dynamic chunking from ws_size (constant across calls -> graph-safe)
  size_t scr_bytes = ws_size - (size_t)((char*)scr16 - (char*)ws);
  // qkv chunks: units of 17 tiles (= 2176 rows = 32 series), 14 units total
  long cap_qg = (long)(scr_bytes / (17ull * 128 * 2304 * 2));
  if (cap_qg > 14) cap_qg = 14;
  if (cap_qg < 1) cap_qg = 1;
  int nch_q = (int)((14 + cap_qg - 1) / cap_qg);
  int gpc = (14 + nch_q - 1) / nch_q;         // 17-tile groups per chunk
  // fc chunks: units of 1 tile (128 rows), 238 tiles total
  long cap_ft = (long)(scr_bytes / (128ull * 3072 * 2));
  if (cap_ft > 238) cap_ft = 238;
  if (cap_ft < 1) cap_ft = 1;
  int nch_f = (int)((238 + cap_ft - 1) / cap_ft);
  int tpc = (238 + nch_f - 1) / nch_f;        // tiles per chunk

  revin_kernel<<<448, 256, 0, stream>>>(x, xr, means, stdev);
  decompose_kernel<<<448, 256, 0, stream>>>(xr, dec);
  embed_kernel<<<1792, 256, 0, stream>>>(dec, in_w, in_b, h);
  keyn_kernel<<<1000, 256, 0, stream>>>(pkey, keyn, kinv);
  xq_kernel<<<448, 256, 0, stream>>>(h, xq);
  zero_kernel<<<1, 64, 0, stream>>>(out + 43008);
  sim_kernel<<<dim3(8, 448), 256, 0, stream>>>(xq, pkey, kinv, simd);
  topk_kernel<<<448, 256, 0, stream>>>(xq, simd, keyn, wpe, h, out + 43008);
  addwpe_kernel<<<NEMB, 256, 0, stream>>>(wpe, h);

  for (int l = 0; l < 6; l++) {
    tcast_kernel<<<dim3(72, 24), 256, 0, stream>>>(qkv_w + (size_t)l * 768 * 2304, wqT, 768, 2304);
    tcast_kernel<<<dim3(24, 24), 256, 0, stream>>>(aw    + (size_t)l * 768 * 768,  waT, 768, 768);
    tcast_kernel<<<dim3(96, 24), 256, 0, stream>>>(fc_w  + (size_t)l * 768 * 3072, wfcT, 768, 3072);
    tcast_kernel<<<dim3(24, 96), 256, 0, stream>>>(mp_w  + (size_t)l * 3072 * 768, wmpT, 3072, 768);

    ln_kernel<<<NTOK, 256, 0, stream>>>(h, abuf16, ln1_g + l * 768, ln1_b + l * 768);
    for (int g0 = 0; g0 < 14; ) {
      int g = (gpc < 14 - g0) ? gpc : (14 - g0);
      int tiles = g * 17, rows = g * 2176, series = g * 32;
      ushort* Ain = abuf16 + (size_t)g0 * 2176 * 768;
      mfma_gemm<<<dim3(18, tiles), 256, 0, stream>>>(
          Ain, wqT, qkv_b + l * 2304, scr16, rows, 2304, 768, 0);
      attn_kernel<<<series * 12, 256, 0, stream>>>(scr16, Ain);
      g0 += g;
    }
    mfma_gemm<<<dim3(6, 238), 256, 0, stream>>>(
        abuf16, waT, ab + l * 768, h, NTOK, 768, 768, 2);
    ln_kernel<<<NTOK, 256, 0, stream>>>(h, abuf16, ln2_g + l * 768, ln2_b + l * 768);
    for (int t0 = 0; t0 < 238; ) {
      int t = (tpc < 238 - t0) ? tpc : (238 - t0);
      mfma_gemm<<<dim3(24, t), 256, 0, stream>>>(
          abuf16 + (size_t)t0 * 128 * 768, wfcT, fc_b + l * 3072, scr16,
          t * 128, 3072, 768, 1);
      mfma_gemm<<<dim3(6, t), 256, 0, stream>>>(
          scr16, wmpT, mp_b + l * 768, h + (size_t)t0 * 128 * 768,
          t * 128, 768, 3072, 2);
      t0 += t;
    }
  }
  ln_kernel<<<NTOK, 256, 0, stream>>>(h, abuf16, lnf_g, lnf_b);
  tcast_kernel<<<dim3(3, 544), 256, 0, stream>>>(out_w, owT16, 17408, 96);
  initof_kernel<<<504, 256, 0, stream>>>(out_b, of);
  splitk_kernel<<<dim3(21, 17), 256, 0, stream>>>(abuf16, owT16, of);
  combine_kernel<<<448, 96, 0, stream>>>(of, stdev, means, out);
}

// Round 8
// 6426.146 us; speedup vs baseline: 1.0307x; 1.0307x over previous
//
#include <hip/hip_runtime.h>
#include <math.h>

// ---------------- constants ----------------
#define NTOK 30464    // 448*68 = 238 tiles of 128
#define NEMB 28672    // 448*64
typedef unsigned short ushort;
typedef __attribute__((ext_vector_type(8))) __bf16 bf16x8_t;
typedef __attribute__((ext_vector_type(4))) float f32x4_t;

#if defined(__has_builtin)
#if __has_builtin(__builtin_amdgcn_global_load_lds)
#define HAS_GLL 1
#endif
#endif

// ---------------- helpers ----------------
__device__ __forceinline__ ushort f2bf(float f) {
  unsigned int u = __float_as_uint(f);
  u += 0x7fffu + ((u >> 16) & 1u);   // RNE (finite inputs)
  return (ushort)(u >> 16);
}
__device__ __forceinline__ float bf2f(ushort u) {
  return __uint_as_float(((unsigned int)u) << 16);
}

#ifdef HAS_GLL
__device__ __forceinline__ void gll16(const ushort* g, ushort* l) {
  __builtin_amdgcn_global_load_lds(
      (const __attribute__((address_space(1))) unsigned int*)g,
      (__attribute__((address_space(3))) unsigned int*)l, 16, 0, 0);
}
#endif

__device__ __forceinline__ float block_reduce_sum(float v, float* scratch) {
  __syncthreads();
  #pragma unroll
  for (int o = 32; o; o >>= 1) v += __shfl_xor(v, o, 64);
  int wid = threadIdx.x >> 6, lane = threadIdx.x & 63;
  if (lane == 0) scratch[wid] = v;
  __syncthreads();
  if (threadIdx.x == 0) {
    float s = 0.f;
    int nw = (blockDim.x + 63) >> 6;
    for (int i = 0; i < nw; i++) s += scratch[i];
    scratch[0] = s;
  }
  __syncthreads();
  return scratch[0];
}

// exact tanh-gelu via sigmoid identity: 0.5x(1+tanh(z)) = x / (1 + e^{-2z})
__device__ __forceinline__ float gelu_f(float x) {
  float z2 = 1.5957691216057308f * (x + 0.044715f * x * x * x);
  return x / (1.0f + __expf(-z2));
}

// ---------------- RevIN ----------------
__global__ __launch_bounds__(256) void revin_kernel(const float* __restrict__ x,
    float* __restrict__ xr, float* __restrict__ means, float* __restrict__ stdev) {
  int bm = blockIdx.x;
  int b = bm / 7, m = bm % 7;
  int tid = threadIdx.x;
  __shared__ float red[8];
  float v0 = x[(size_t)b * 3584 + (size_t)tid * 7 + m];
  float v1 = x[(size_t)b * 3584 + (size_t)(tid + 256) * 7 + m];
  float s  = block_reduce_sum(v0 + v1, red);
  float ss = block_reduce_sum(v0 * v0 + v1 * v1, red);
  float mean = s * (1.0f / 512.0f);
  float var  = ss * (1.0f / 512.0f) - mean * mean;
  float sd = sqrtf(var + 1e-5f);
  if (tid == 0) { means[bm] = mean; stdev[bm] = sd; }
  float inv = 1.0f / sd;
  xr[(size_t)bm * 512 + tid]       = (v0 - mean) * inv;
  xr[(size_t)bm * 512 + tid + 256] = (v1 - mean) * inv;
}

// ---------------- decompose ----------------
__global__ __launch_bounds__(256) void decompose_kernel(const float* __restrict__ xr,
    float* __restrict__ dec) {
  int n = blockIdx.x, tid = threadIdx.x;
  __shared__ float xv[512];
  __shared__ float tr[512];
  __shared__ float sumS[24];
  for (int l = tid; l < 512; l += 256) xv[l] = xr[(size_t)n * 512 + l];
  if (tid < 24) sumS[tid] = 0.f;
  __syncthreads();
  for (int l = tid; l < 512; l += 256) {
    int t0 = l - 12; t0 = t0 < 0 ? 0 : (t0 > 488 ? 488 : t0);
    float s = 0.f;
    #pragma unroll
    for (int j = 0; j < 24; j++) s += xv[t0 + j];
    float t = s * (1.0f / 24.0f);
    tr[l] = t;
    atomicAdd(&sumS[l % 24], xv[l] - t);
  }
  __syncthreads();
  if (tid < 24) sumS[tid] *= (tid < 8) ? (1.0f / 22.0f) : (1.0f / 21.0f);
  __syncthreads();
  float* dp = dec + (size_t)n * 1536;
  for (int l = tid; l < 512; l += 256) {
    float t = tr[l], se = sumS[l % 24];
    dp[l] = t;
    dp[512 + l] = se;
    dp[1024 + l] = xv[l] - t - se;
  }
}

// ---------------- patch + embed -> h rows 4..67 (NO wpe yet) ----------------
__global__ __launch_bounds__(256) void embed_kernel(const float* __restrict__ dec,
    const float* __restrict__ in_w, const float* __restrict__ in_b, float* __restrict__ h) {
  int blk = blockIdx.x;            // 448 * 4
  int n = blk >> 2, pg = blk & 3;  // series, patch-group of 16
  int tid = threadIdx.x;
  __shared__ __align__(16) float tok[16][48];
  for (int idx = tid; idx < 768; idx += 256) {
    int p = idx / 48, k = idx - p * 48;
    int c = k >> 4, j = k & 15;
    int l = (pg * 16 + p) * 8 + j; if (l > 511) l = 511;
    tok[p][k] = dec[(size_t)n * 1536 + (size_t)c * 512 + l];
  }
  __syncthreads();
  const int d0 = tid, d1 = tid + 256, d2 = tid + 512;
  float acc[16][3];
  float b0 = in_b[d0], b1 = in_b[d1], b2 = in_b[d2];
  #pragma unroll
  for (int p = 0; p < 16; p++) { acc[p][0] = b0; acc[p][1] = b1; acc[p][2] = b2; }
  for (int kq = 0; kq < 12; kq++) {
    float w0[4], w1[4], w2[4];
    #pragma unroll
    for (int kk = 0; kk < 4; kk++) {
      const float* wp = in_w + (size_t)(kq * 4 + kk) * 768;
      w0[kk] = wp[d0]; w1[kk] = wp[d1]; w2[kk] = wp[d2];
    }
    #pragma unroll
    for (int p = 0; p < 16; p++) {
      float4 t = *(const float4*)&tok[p][kq * 4];
      acc[p][0] += t.x * w0[0]; acc[p][1] += t.x * w1[0]; acc[p][2] += t.x * w2[0];
      acc[p][0] += t.y * w0[1]; acc[p][1] += t.y * w1[1]; acc[p][2] += t.y * w2[1];
      acc[p][0] += t.z * w0[2]; acc[p][1] += t.z * w1[2]; acc[p][2] += t.z * w2[2];
      acc[p][0] += t.w * w0[3]; acc[p][1] += t.w * w1[3]; acc[p][2] += t.w * w2[3];
    }
  }
  #pragma unroll
  for (int p = 0; p < 16; p++) {
    float* outp = h + ((size_t)n * 68 + 4 + pg * 16 + p) * 768;
    outp[d0] = acc[p][0]; outp[d1] = acc[p][1]; outp[d2] = acc[p][2];
  }
}

// ---------------- key normalization ----------------
__global__ __launch_bounds__(256) void keyn_kernel(const float* __restrict__ pkey,
    float* __restrict__ keyn, double* __restrict__ kinv) {
  int k = blockIdx.x, tid = threadIdx.x;
  __shared__ double redd[4];
  float v[3];
  double ss = 0.0;
  #pragma unroll
  for (int i = 0; i < 3; i++) {
    v[i] = pkey[(size_t)k * 768 + tid + i * 256];
    ss += (double)v[i] * (double)v[i];
  }
  #pragma unroll
  for (int o = 32; o; o >>= 1) ss += __shfl_xor(ss, o, 64);
  int wid = tid >> 6, lane = tid & 63;
  if (lane == 0) redd[wid] = ss;
  __syncthreads();
  if (tid == 0) redd[0] = redd[0] + redd[1] + redd[2] + redd[3];
  __syncthreads();
  ss = redd[0];
  double inv = 1.0 / sqrt(ss > 1e-12 ? ss : 1e-12);
  #pragma unroll
  for (int i = 0; i < 3; i++)
    keyn[(size_t)k * 768 + tid + i * 256] = (float)((double)v[i] * inv);
  if (tid == 0) kinv[k] = inv;
}

// ---------------- xq ----------------
__global__ __launch_bounds__(256) void xq_kernel(const float* __restrict__ h,
    float* __restrict__ xq) {
  int n = blockIdx.x, tid = threadIdx.x;
  __shared__ float red[8];
  float vals[3];
  float ssl = 0.f;
  #pragma unroll
  for (int i = 0; i < 3; i++) {
    int d = tid + i * 256;
    const float* p = h + ((size_t)n * 68 + 4) * 768 + d;
    float s = 0.f;
    for (int pc = 0; pc < 64; pc++) s += p[(size_t)pc * 768];
    s *= (1.0f / 64.0f);
    vals[i] = s; ssl += s * s;
  }
  float ss = block_reduce_sum(ssl, red);
  float inv = rsqrtf(fmaxf(ss, 1e-12f));
  #pragma unroll
  for (int i = 0; i < 3; i++)
    xq[(size_t)n * 768 + tid + i * 256] = vals[i] * inv;
}

__global__ void zero_kernel(float* p) {
  if (threadIdx.x == 0 && blockIdx.x == 0) p[0] = 0.f;
}

// ---------------- sim matrix (f64, high-parallelism) ----------------
__global__ __launch_bounds__(256) void sim_kernel(
    const float* __restrict__ xq, const float* __restrict__ pkey,
    const double* __restrict__ kinv, double* __restrict__ simd) {
  int n = blockIdx.y;
  int kbase = blockIdx.x * 128;
  int tid = threadIdx.x;
  __shared__ __align__(16) float xqv[768];
  #pragma unroll
  for (int i = 0; i < 3; i++) xqv[tid + i * 256] = xq[(size_t)n * 768 + tid + i * 256];
  __syncthreads();
  int lane = tid & 63, wid = tid >> 6;
  double xd[12];
  #pragma unroll
  for (int i = 0; i < 12; i++) xd[i] = (double)xqv[lane * 12 + i];

  for (int k4 = kbase + wid * 4; k4 < kbase + 128; k4 += 16) {
    int kt[4];
    #pragma unroll
    for (int t = 0; t < 4; t++) { int k = k4 + t; kt[t] = k < 1000 ? k : 999; }
    float4 v[4][3];
    #pragma unroll
    for (int t = 0; t < 4; t++)
      #pragma unroll
      for (int j = 0; j < 3; j++)
        v[t][j] = *(const float4*)(pkey + (size_t)kt[t] * 768 + lane * 12 + j * 4);
    double a[4] = {0.0, 0.0, 0.0, 0.0};
    #pragma unroll
    for (int t = 0; t < 4; t++)
      #pragma unroll
      for (int j = 0; j < 3; j++) {
        a[t] += (double)v[t][j].x * xd[4 * j + 0];
        a[t] += (double)v[t][j].y * xd[4 * j + 1];
        a[t] += (double)v[t][j].z * xd[4 * j + 2];
        a[t] += (double)v[t][j].w * xd[4 * j + 3];
      }
    #pragma unroll
    for (int t = 0; t < 4; t++)
      #pragma unroll
      for (int o = 32; o; o >>= 1) a[t] += __shfl_xor(a[t], o, 64);
    if (lane == 0) {
      #pragma unroll
      for (int t = 0; t < 4; t++) {
        int k = k4 + t;
        if (k < 1000) simd[(size_t)n * 1000 + k] = a[t] * kinv[k];
      }
    }
  }
}

// ---------------- top-4 + prompt rows + reduce_sim ----------------
__global__ __launch_bounds__(256) void topk_kernel(
    const float* __restrict__ xq, const double* __restrict__ simd_g,
    const float* __restrict__ keyn, const float* __restrict__ wpe,
    float* __restrict__ h, float* __restrict__ rs_out) {
  int n = blockIdx.x, tid = threadIdx.x;
  __shared__ __align__(16) float xqv[768];
  __shared__ double simd_s[1000];
  __shared__ int idxs[4];
  __shared__ double redv[4];
  __shared__ int redi[4];
  __shared__ float red2[8];
  #pragma unroll
  for (int i = 0; i < 3; i++) xqv[tid + i * 256] = xq[(size_t)n * 768 + tid + i * 256];
  for (int k = tid; k < 1000; k += 256) simd_s[k] = simd_g[(size_t)n * 1000 + k];
  __syncthreads();
  int lane = tid & 63, wid = tid >> 6;
  for (int r = 0; r < 4; r++) {
    double bv = -1e300; int bi = 0x7fffffff;
    for (int k = tid; k < 1000; k += 256) {
      double v = simd_s[k];
      if (v > bv || (v == bv && k < bi)) { bv = v; bi = k; }
    }
    #pragma unroll
    for (int off = 32; off; off >>= 1) {
      double ov = __shfl_xor(bv, off, 64);
      int oi = __shfl_xor(bi, off, 64);
      if (ov > bv || (ov == bv && oi < bi)) { bv = ov; bi = oi; }
    }
    if (lane == 0) { redv[wid] = bv; redi[wid] = bi; }
    __syncthreads();
    if (tid == 0) {
      double fv = redv[0]; int fi = redi[0];
      for (int w = 1; w < 4; w++)
        if (redv[w] > fv || (redv[w] == fv && redi[w] < fi)) { fv = redv[w]; fi = redi[w]; }
      idxs[r] = fi; simd_s[fi] = -1e300;
    }
    __syncthreads();
  }
  float part = 0.f;
  for (int r = 0; r < 4; r++) {
    int ki = idxs[r];
    const float* kp = keyn + (size_t)ki * 768;
    const float* wp = wpe + (size_t)r * 768;
    float* hp = h + ((size_t)n * 68 + r) * 768;
    #pragma unroll
    for (int i = 0; i < 3; i++) {
      int d = tid + i * 256;
      float kv = kp[d];
      hp[d] = kv + wp[d];
      part += kv * xqv[d];
    }
  }
  part = block_reduce_sum(part, red2);
  if (tid == 0) atomicAdd(rs_out, part * (1.0f / 448.0f));
}

// ---------------- h rows 4..67 += wpe ----------------
__global__ __launch_bounds__(256) void addwpe_kernel(const float* __restrict__ wpe,
    float* __restrict__ h) {
  int np = blockIdx.x;
  int n = np >> 6, p = np & 63;
  int tid = threadIdx.x;
  const float* wp = wpe + (size_t)(4 + p) * 768;
  float* hp = h + ((size_t)n * 68 + 4 + p) * 768;
  #pragma unroll
  for (int i = 0; i < 3; i++) { int d = tid + i * 256; hp[d] += wp[d]; }
}

// ---------------- LayerNorm -> bf16 (wave-per-row, barrier-free) ----------------
// 4 rows/block (grid NTOK/4). Lane holds 12 consecutive f32 (3x float4);
// interleaved shfl_xor chain gives sum+sumsq; bf16 out as 8B stores.
__global__ __launch_bounds__(256) void ln_kernel(const float* __restrict__ src,
    ushort* __restrict__ dst, const float* __restrict__ g, const float* __restrict__ b) {
  int wid = threadIdx.x >> 6, lane = threadIdx.x & 63;
  size_t row = (size_t)blockIdx.x * 4 + wid;
  const float* xp = src + row * 768;
  ushort* yp = dst + row * 768;
  float4 v[3];
  float s = 0.f, ss = 0.f;
  #pragma unroll
  for (int j = 0; j < 3; j++) {
    v[j] = *(const float4*)(xp + lane * 4 + j * 256);
    s  += v[j].x + v[j].y + v[j].z + v[j].w;
    ss += v[j].x * v[j].x + v[j].y * v[j].y + v[j].z * v[j].z + v[j].w * v[j].w;
  }
  #pragma unroll
  for (int o = 32; o; o >>= 1) {
    s  += __shfl_xor(s, o, 64);
    ss += __shfl_xor(ss, o, 64);
  }
  float mean = s * (1.0f / 768.0f);
  float var  = ss * (1.0f / 768.0f) - mean * mean;
  float rs = rsqrtf(var + 1e-5f);
  #pragma unroll
  for (int j = 0; j < 3; j++) {
    int c = lane * 4 + j * 256;
    float4 gv = *(const float4*)(g + c);
    float4 bv = *(const float4*)(b + c);
    ushort o4[4];
    o4[0] = f2bf((v[j].x - mean) * rs * gv.x + bv.x);
    o4[1] = f2bf((v[j].y - mean) * rs * gv.y + bv.y);
    o4[2] = f2bf((v[j].z - mean) * rs * gv.z + bv.z);
    o4[3] = f2bf((v[j].w - mean) * rs * gv.w + bv.w);
    *(uint2*)(yp + c) = *(const uint2*)o4;
  }
}

// ---------------- cast+transpose weights: W[K][N] f32 -> WT[N][K] bf16 ----------------
__global__ __launch_bounds__(256) void tcast_kernel(const float* __restrict__ W,
    ushort* __restrict__ WT, int K, int N) {
  __shared__ ushort t[32][33];
  int n0 = blockIdx.x * 32, k0 = blockIdx.y * 32;
  int tx = threadIdx.x & 31, ty = threadIdx.x >> 5;   // 32 x 8
  #pragma unroll
  for (int i = 0; i < 4; i++) {
    int kk = ty + i * 8;
    t[kk][tx] = f2bf(W[(size_t)(k0 + kk) * N + n0 + tx]);
  }
  __syncthreads();
  #pragma unroll
  for (int i = 0; i < 4; i++) {
    int nn = ty + i * 8;
    WT[(size_t)(n0 + nn) * K + k0 + tx] = t[tx][nn];
  }
}

// ---------------- bf16 MFMA GEMM (m97-style global_load_lds staging) ----------------
// C = A(MxK) @ WT(NxK)^T + bias. 128x128 tile, 4 waves, 16x16x32 bf16.
// mode 0: C bf16;  1: C bf16 w/ gelu;  2: C fp32 += (residual)
__global__ __launch_bounds__(256) void mfma_gemm(const ushort* __restrict__ A,
    const ushort* __restrict__ WT, const float* __restrict__ bias, void* __restrict__ Cp,
    int M, int N, int K, int mode) {
  __shared__ ushort As[128 * 32];
  __shared__ ushort Bs[128 * 32];
  const int tid = threadIdx.x;
  const int row0 = blockIdx.y * 128, col0 = blockIdx.x * 128;
  const int w = tid >> 6, lane = tid & 63;
  const int wm = w >> 1, wn = w & 1;
  const int lm = lane & 15, quad = lane >> 4;
  const int srow = w * 16 + (lane >> 2);
  const int scol = (lane & 3) * 8;
  const ushort* agp0 = A  + (size_t)(row0 + srow)      * K + scol;
  const ushort* agp1 = A  + (size_t)(row0 + 64 + srow) * K + scol;
  const ushort* bgp0 = WT + (size_t)(col0 + srow)      * K + scol;
  const ushort* bgp1 = WT + (size_t)(col0 + 64 + srow) * K + scol;
  ushort* al0 = &As[w * 512];
  ushort* al1 = &As[2048 + w * 512];
  ushort* bl0 = &Bs[w * 512];
  ushort* bl1 = &Bs[2048 + w * 512];
  f32x4_t acc[4][4];
  #pragma unroll
  for (int mi = 0; mi < 4; mi++)
    #pragma unroll
    for (int ni = 0; ni < 4; ni++) acc[mi][ni] = (f32x4_t)(0.0f);

  for (int kb = 0; kb < K; kb += 32) {
    __syncthreads();
#ifdef HAS_GLL
    gll16(agp0 + kb, al0);
    gll16(agp1 + kb, al1);
    gll16(bgp0 + kb, bl0);
    gll16(bgp1 + kb, bl1);
#else
    {
      uint4 va0 = *(const uint4*)(agp0 + kb);
      uint4 va1 = *(const uint4*)(agp1 + kb);
      uint4 vb0 = *(const uint4*)(bgp0 + kb);
      uint4 vb1 = *(const uint4*)(bgp1 + kb);
      *(uint4*)&al0[lane * 8] = va0;
      *(uint4*)&al1[lane * 8] = va1;
      *(uint4*)&bl0[lane * 8] = vb0;
      *(uint4*)&bl1[lane * 8] = vb1;
    }
#endif
    __syncthreads();
    bf16x8_t af[4], bfr[4];
    #pragma unroll
    for (int mi = 0; mi < 4; mi++)
      af[mi] = *(const bf16x8_t*)&As[(wm * 64 + mi * 16 + lm) * 32 + quad * 8];
    #pragma unroll
    for (int ni = 0; ni < 4; ni++)
      bfr[ni] = *(const bf16x8_t*)&Bs[(wn * 64 + ni * 16 + lm) * 32 + quad * 8];
    #pragma unroll
    for (int mi = 0; mi < 4; mi++)
      #pragma unroll
      for (int ni = 0; ni < 4; ni++)
        acc[mi][ni] = __builtin_amdgcn_mfma_f32_16x16x32_bf16(af[mi], bfr[ni], acc[mi][ni], 0, 0, 0);
  }
  #pragma unroll
  for (int mi = 0; mi < 4; mi++) {
    #pragma unroll
    for (int ni = 0; ni < 4; ni++) {
      int gcol = col0 + wn * 64 + ni * 16 + lm;
      float bz = bias[gcol];
      #pragma unroll
      for (int r = 0; r < 4; r++) {
        int grow = row0 + wm * 64 + mi * 16 + quad * 4 + r;
        float v = acc[mi][ni][r] + bz;
        if (mode == 0)      ((ushort*)Cp)[(size_t)grow * N + gcol] = f2bf(v);
        else if (mode == 1) ((ushort*)Cp)[(size_t)grow * N + gcol] = f2bf(gelu_f(v));
        else { float* c = (float*)Cp + (size_t)grow * N + gcol; *c += v; }
      }
    }
  }
}

// ---------------- MFMA attention: block = (series-in-chunk, head) ----------------
__global__ __launch_bounds__(256) void attn_kernel(const ushort* __restrict__ qkvc,
    ushort* __restrict__ obase) {
  __shared__ __align__(16) ushort qk[2 * 80 * 64];
  __shared__ __align__(16) ushort vt[64][96];
  __shared__ __align__(16) float  sS[68][80];
  ushort* qs = qk;
  ushort* ks = qk + 80 * 64;
  ushort (*P)[96] = (ushort(*)[96])qk;

  int nh = blockIdx.x;
  int nl = nh / 12, hh = nh % 12;
  int tid = threadIdx.x;
  const int w = tid >> 6, lane = tid & 63;
  const int lm = lane & 15, quad = lane >> 4;
  const ushort* base = qkvc + (size_t)nl * 68 * 2304 + hh * 64;

  // vectorized load: one uint4 (8 bf16) per matrix per chunk; 68 rows x 8 segs
  for (int idx = tid; idx < 68 * 8; idx += 256) {
    int t = idx >> 3, seg = (idx & 7) * 8;
    const ushort* rp = base + (size_t)t * 2304 + seg;
    uint4 q = *(const uint4*)(rp);
    uint4 k = *(const uint4*)(rp + 768);
    uint4 v = *(const uint4*)(rp + 1536);
    *(uint4*)&qs[t * 64 + seg] = q;
    *(uint4*)&ks[t * 64 + seg] = k;
    const ushort* pv = (const ushort*)&v;
    #pragma unroll
    for (int j = 0; j < 8; j++) vt[seg + j][t] = pv[j];
  }
  for (int idx = tid; idx < 64 * 28; idx += 256) {
    int d = idx / 28, t = 68 + idx % 28;
    vt[d][t] = 0;
  }
  __syncthreads();

  for (int t5 = w; t5 < 25; t5 += 4) {
    int mi = t5 / 5, ni = t5 % 5;
    bf16x8_t a0 = *(const bf16x8_t*)&qs[(mi * 16 + lm) * 64 + quad * 8];
    bf16x8_t a1 = *(const bf16x8_t*)&qs[(mi * 16 + lm) * 64 + 32 + quad * 8];
    bf16x8_t b0 = *(const bf16x8_t*)&ks[(ni * 16 + lm) * 64 + quad * 8];
    bf16x8_t b1 = *(const bf16x8_t*)&ks[(ni * 16 + lm) * 64 + 32 + quad * 8];
    f32x4_t acc = (f32x4_t)(0.0f);
    acc = __builtin_amdgcn_mfma_f32_16x16x32_bf16(a0, b0, acc, 0, 0, 0);
    acc = __builtin_amdgcn_mfma_f32_16x16x32_bf16(a1, b1, acc, 0, 0, 0);
    int col = ni * 16 + lm;
    #pragma unroll
    for (int r = 0; r < 4; r++) {
      int row = mi * 16 + quad * 4 + r;
      if (row < 68) {
        float sv = (col > row || col >= 68) ? -1e9f : acc[r] * 0.125f;
        sS[row][col] = sv;
      }
    }
  }
  __syncthreads();

  // wave-parallel softmax: each 4-lane quad owns a row
  {
    int q = tid >> 2, lq = tid & 3;
    for (int r = q; r < 68; r += 64) {
      float mx = -1e30f;
      for (int c = lq; c < 80; c += 4) mx = fmaxf(mx, sS[r][c]);
      mx = fmaxf(mx, __shfl_xor(mx, 1, 64));
      mx = fmaxf(mx, __shfl_xor(mx, 2, 64));
      float s = 0.f;
      for (int c = lq; c < 80; c += 4) {
        float e = __expf(sS[r][c] - mx);
        sS[r][c] = e; s += e;
      }
      s += __shfl_xor(s, 1, 64);
      s += __shfl_xor(s, 2, 64);
      float inv = 1.0f / s;
      for (int c = lq; c < 80; c += 4) P[r][c] = f2bf(sS[r][c] * inv);
      for (int c = 80 + lq; c < 96; c += 4) P[r][c] = 0;
    }
    for (int idx = tid; idx < 12 * 96; idx += 256) {
      int r = 68 + idx / 96, c = idx % 96;
      P[r][c] = 0;
    }
  }
  __syncthreads();

  for (int t5 = w; t5 < 20; t5 += 4) {
    int mi = t5 % 5, ni = t5 / 5;
    f32x4_t acc = (f32x4_t)(0.0f);
    #pragma unroll
    for (int kk = 0; kk < 3; kk++) {
      bf16x8_t a = *(const bf16x8_t*)&P[mi * 16 + lm][kk * 32 + quad * 8];
      bf16x8_t b = *(const bf16x8_t*)&vt[ni * 16 + lm][kk * 32 + quad * 8];
      acc = __builtin_amdgcn_mfma_f32_16x16x32_bf16(a, b, acc, 0, 0, 0);
    }
    int col = ni * 16 + lm;
    #pragma unroll
    for (int r = 0; r < 4; r++) {
      int row = mi * 16 + quad * 4 + r;
      if (row < 68)
        obase[((size_t)nl * 68 + row) * 768 + hh * 64 + col] = f2bf(acc[r]);
    }
  }
}

// ---------------- final head ----------------
__global__ __launch_bounds__(256) void initof_kernel(const float* __restrict__ ob,
    float* __restrict__ of) {
  int i = blockIdx.x * 256 + threadIdx.x;
  of[i] = ob[i % 96];
}

// MFMA split-K head GEMM: of(1344x96) += A(1344x17408) @ WT(96x17408)^T
__global__ __launch_bounds__(256) void splitk_kernel(const ushort* __restrict__ A,
    const ushort* __restrict__ WT, float* __restrict__ of) {
  __shared__ ushort As[64 * 32];
  __shared__ ushort Ws[96 * 32];
  const int tid = threadIdx.x;
  const int row0 = blockIdx.x * 64;
  const int k0 = blockIdx.y * 1024;
  const int w = tid >> 6, lane = tid & 63;
  const int lm = lane & 15, quad = lane >> 4;
  const ushort* agp  = A  + (size_t)(row0 + (tid >> 2)) * 17408 + (tid & 3) * 8;
  const ushort* wgp1 = WT + (size_t)(tid >> 2) * 17408 + (tid & 3) * 8;
  const ushort* wgp2 = WT + (size_t)(64 + (tid >> 2)) * 17408 + (tid & 3) * 8;
  ushort* asl  = &As[w * 512];
  ushort* wsl1 = &Ws[w * 512];
  ushort* wsl2 = &Ws[2048 + w * 512];
  f32x4_t acc[6];
  #pragma unroll
  for (int ni = 0; ni < 6; ni++) acc[ni] = (f32x4_t)(0.0f);
  for (int kb = k0; kb < k0 + 1024; kb += 32) {
    __syncthreads();
#ifdef HAS_GLL
    gll16(agp + kb, asl);
    gll16(wgp1 + kb, wsl1);
    if (w < 2) gll16(wgp2 + kb, wsl2);
#else
    {
      uint4 va = *(const uint4*)(agp + kb);
      *(uint4*)&As[tid * 8] = va;
      uint4 vw = *(const uint4*)(wgp1 + kb);
      *(uint4*)&Ws[tid * 8] = vw;
      if (tid < 128) {
        uint4 vw2 = *(const uint4*)(wgp2 + kb);
        *(uint4*)&Ws[2048 + tid * 8] = vw2;
      }
    }
#endif
    __syncthreads();
    bf16x8_t af = *(const bf16x8_t*)&As[(w * 16 + lm) * 32 + quad * 8];
    #pragma unroll
    for (int ni = 0; ni < 6; ni++) {
      bf16x8_t bfrag = *(const bf16x8_t*)&Ws[(ni * 16 + lm) * 32 + quad * 8];
      acc[ni] = __builtin_amdgcn_mfma_f32_16x16x32_bf16(af, bfrag, acc[ni], 0, 0, 0);
    }
  }
  #pragma unroll
  for (int ni = 0; ni < 6; ni++) {
    int col = ni * 16 + lm;
    #pragma unroll
    for (int r = 0; r < 4; r++) {
      int grow = row0 + w * 16 + quad * 4 + r;
      atomicAdd(&of[(size_t)grow * 96 + col], acc[ni][r]);
    }
  }
}

__global__ void combine_kernel(const float* __restrict__ of, const float* __restrict__ stdev,
    const float* __restrict__ means, float* __restrict__ out) {
  int bm = blockIdx.x;
  int b = bm / 7, m = bm % 7;
  int j = threadIdx.x;
  if (j < 96) {
    float s = of[(size_t)(bm * 3 + 0) * 96 + j]
            + of[(size_t)(bm * 3 + 1) * 96 + j]
            + of[(size_t)(bm * 3 + 2) * 96 + j];
    out[(size_t)b * 672 + (size_t)j * 7 + m] = s * stdev[bm] + means[bm];
  }
}

// ---------------- launcher ----------------
extern "C" void kernel_launch(void* const* d_in, const int* in_sizes, int n_in,
                              void* d_out, int out_size, void* d_ws, size_t ws_size,
                              hipStream_t stream) {
  (void)in_sizes; (void)n_in; (void)out_size;
  const float* x     = (const float*)d_in[0];
  const float* in_w  = (const float*)d_in[2];
  const float* in_b  = (const float*)d_in[3];
  const float* pkey  = (const float*)d_in[4];
  const float* wpe   = (const float*)d_in[5];
  const float* ln1_g = (const float*)d_in[6];
  const float* ln1_b = (const float*)d_in[7];
  const float* qkv_w = (const float*)d_in[8];
  const float* qkv_b = (const float*)d_in[9];
  const float* aw    = (const float*)d_in[10];
  const float* ab    = (const float*)d_in[11];
  const float* ln2_g = (const float*)d_in[12];
  const float* ln2_b = (const float*)d_in[13];
  const float* fc_w  = (const float*)d_in[14];
  const float* fc_b  = (const float*)d_in[15];
  const float* mp_w  = (const float*)d_in[16];
  const float* mp_b  = (const float*)d_in[17];
  const float* lnf_g = (const float*)d_in[18];
  const float* lnf_b = (const float*)d_in[19];
  const float* out_w = (const float*)d_in[20];
  const float* out_b = (const float*)d_in[21];
  float* out = (float*)d_out;
  float* ws  = (float*)d_ws;

  // workspace layout: small (2,161,664 f) + h + abuf16 + w16 + scr (rest)
  float* means = ws;
  float* stdev = ws + 512;
  float* xr    = ws + 1024;
  float* dec   = xr + 229376;
  float* keyn  = dec + 688128;
  double* kinv = (double*)(keyn + 768000);
  float* xq    = keyn + 768000 + 2048;
  float* of    = xq + 344064;
  float* h     = of + 129024;                 // 23,396,352 f
  ushort* abuf16 = (ushort*)(h + 23396352);   // 23,396,352 us
  ushort* w16    = abuf16 + 23396352;         // 7,077,888 us
  ushort* scr16  = w16 + 7077888;             // remainder
  ushort* owT16  = scr16;                     // alias (only used after layers)

  // sim matrix (448 x 1000 f64 = 3.584 MB) reuses the xr+dec region
  // (3.67 MB, dead after embed_kernel; 8B-aligned: ws+4096 bytes)
  double* simd = (double*)xr;

  ushort* wqT  = w16;                         // 2304 x 768
  ushort* waT  = wqT + 2304 * 768;            // 768 x 768
  ushort* wfcT = waT + 768 * 768;             // 3072 x 768
  ushort* wmpT = wfcT + 3072 * 768;           // 768 x 3072

  // dynamic chunking from ws_size (constant across calls -> graph-safe)
  size_t scr_bytes = ws_size - (size_t)((char*)scr16 - (char*)ws);
  // qkv chunks: units of 17 tiles (= 2176 rows = 32 series), 14 units total
  long cap_qg = (long)(scr_bytes / (17ull * 128 * 2304 * 2));
  if (cap_qg > 14) cap_qg = 14;
  if (cap_qg < 1) cap_qg = 1;
  int nch_q = (int)((14 + cap_qg - 1) / cap_qg);
  int gpc = (14 + nch_q - 1) / nch_q;         // 17-tile groups per chunk
  // fc chunks: units of 1 tile (128 rows), 238 tiles total
  long cap_ft = (long)(scr_bytes / (128ull * 3072 * 2));
  if (cap_ft > 238) cap_ft = 238;
  if (cap_ft < 1) cap_ft = 1;
  int nch_f = (int)((238 + cap_ft - 1) / cap_ft);
  int tpc = (238 + nch_f - 1) / nch_f;        // tiles per chunk

  revin_kernel<<<448, 256, 0, stream>>>(x, xr, means, stdev);
  decompose_kernel<<<448, 256, 0, stream>>>(xr, dec);
  embed_kernel<<<1792, 256, 0, stream>>>(dec, in_w, in_b, h);
  keyn_kernel<<<1000, 256, 0, stream>>>(pkey, keyn, kinv);
  xq_kernel<<<448, 256, 0, stream>>>(h, xq);
  zero_kernel<<<1, 64, 0, stream>>>(out + 43008);
  sim_kernel<<<dim3(8, 448), 256, 0, stream>>>(xq, pkey, kinv, simd);
  topk_kernel<<<448, 256, 0, stream>>>(xq, simd, keyn, wpe, h, out + 43008);
  addwpe_kernel<<<NEMB, 256, 0, stream>>>(wpe, h);

  for (int l = 0; l < 6; l++) {
    tcast_kernel<<<dim3(72, 24), 256, 0, stream>>>(qkv_w + (size_t)l * 768 * 2304, wqT, 768, 2304);
    tcast_kernel<<<dim3(24, 24), 256, 0, stream>>>(aw    + (size_t)l * 768 * 768,  waT, 768, 768);
    tcast_kernel<<<dim3(96, 24), 256, 0, stream>>>(fc_w  + (size_t)l * 768 * 3072, wfcT, 768, 3072);
    tcast_kernel<<<dim3(24, 96), 256, 0, stream>>>(mp_w  + (size_t)l * 3072 * 768, wmpT, 3072, 768);

    ln_kernel<<<NTOK / 4, 256, 0, stream>>>(h, abuf16, ln1_g + l * 768, ln1_b + l * 768);
    for (int g0 = 0; g0 < 14; ) {
      int g = (gpc < 14 - g0) ? gpc : (14 - g0);
      int tiles = g * 17, rows = g * 2176, series = g * 32;
      ushort* Ain = abuf16 + (size_t)g0 * 2176 * 768;
      mfma_gemm<<<dim3(18, tiles), 256, 0, stream>>>(
          Ain, wqT, qkv_b + l * 2304, scr16, rows, 2304, 768, 0);
      attn_kernel<<<series * 12, 256, 0, stream>>>(scr16, Ain);
      g0 += g;
    }
    mfma_gemm<<<dim3(6, 238), 256, 0, stream>>>(
        abuf16, waT, ab + l * 768, h, NTOK, 768, 768, 2);
    ln_kernel<<<NTOK / 4, 256, 0, stream>>>(h, abuf16, ln2_g + l * 768, ln2_b + l * 768);
    for (int t0 = 0; t0 < 238; ) {
      int t = (tpc < 238 - t0) ? tpc : (238 - t0);
      mfma_gemm<<<dim3(24, t), 256, 0, stream>>>(
          abuf16 + (size_t)t0 * 128 * 768, wfcT, fc_b + l * 3072, scr16,
          t * 128, 3072, 768, 1);
      mfma_gemm<<<dim3(6, t), 256, 0, stream>>>(
          scr16, wmpT, mp_b + l * 768, h + (size_t)t0 * 128 * 768,
          t * 128, 768, 3072, 2);
      t0 += t;
    }
  }
  ln_kernel<<<NTOK / 4, 256, 0, stream>>>(h, abuf16, lnf_g, lnf_b);
  tcast_kernel<<<dim3(3, 544), 256, 0, stream>>>(out_w, owT16, 17408, 96);
  initof_kernel<<<504, 256, 0, stream>>>(out_b, of);
  splitk_kernel<<<dim3(21, 17), 256, 0, stream>>>(abuf16, owT16, of);
  combine_kernel<<<448, 96, 0, stream>>>(of, stdev, means, out);
}

// Round 10
// 6400.237 us; speedup vs baseline: 1.0348x; 1.0040x over previous
//
#include <hip/hip_runtime.h>
#include <math.h>

// ---------------- constants ----------------
#define NTOK 30464    // 448*68 = 238 tiles of 128
#define NEMB 28672    // 448*64
typedef unsigned short ushort;
typedef __attribute__((ext_vector_type(8))) __bf16 bf16x8_t;
typedef __attribute__((ext_vector_type(4))) float f32x4_t;

#if defined(__has_builtin)
#if __has_builtin(__builtin_amdgcn_global_load_lds)
#define HAS_GLL 1
#endif
#endif

// ---------------- helpers ----------------
__device__ __forceinline__ ushort f2bf(float f) {
  unsigned int u = __float_as_uint(f);
  u += 0x7fffu + ((u >> 16) & 1u);   // RNE (finite inputs)
  return (ushort)(u >> 16);
}
__device__ __forceinline__ float bf2f(ushort u) {
  return __uint_as_float(((unsigned int)u) << 16);
}

#ifdef HAS_GLL
__device__ __forceinline__ void gll16(const ushort* g, ushort* l) {
  __builtin_amdgcn_global_load_lds(
      (const __attribute__((address_space(1))) unsigned int*)g,
      (__attribute__((address_space(3))) unsigned int*)l, 16, 0, 0);
}
#endif

__device__ __forceinline__ float block_reduce_sum(float v, float* scratch) {
  __syncthreads();
  #pragma unroll
  for (int o = 32; o; o >>= 1) v += __shfl_xor(v, o, 64);
  int wid = threadIdx.x >> 6, lane = threadIdx.x & 63;
  if (lane == 0) scratch[wid] = v;
  __syncthreads();
  if (threadIdx.x == 0) {
    float s = 0.f;
    int nw = (blockDim.x + 63) >> 6;
    for (int i = 0; i < nw; i++) s += scratch[i];
    scratch[0] = s;
  }
  __syncthreads();
  return scratch[0];
}

// exact tanh-gelu via sigmoid identity: 0.5x(1+tanh(z)) = x / (1 + e^{-2z})
__device__ __forceinline__ float gelu_f(float x) {
  float z2 = 1.5957691216057308f * (x + 0.044715f * x * x * x);
  return x / (1.0f + __expf(-z2));
}

// ---------------- RevIN ----------------
__global__ __launch_bounds__(256) void revin_kernel(const float* __restrict__ x,
    float* __restrict__ xr, float* __restrict__ means, float* __restrict__ stdev) {
  int bm = blockIdx.x;
  int b = bm / 7, m = bm % 7;
  int tid = threadIdx.x;
  __shared__ float red[8];
  float v0 = x[(size_t)b * 3584 + (size_t)tid * 7 + m];
  float v1 = x[(size_t)b * 3584 + (size_t)(tid + 256) * 7 + m];
  float s  = block_reduce_sum(v0 + v1, red);
  float ss = block_reduce_sum(v0 * v0 + v1 * v1, red);
  float mean = s * (1.0f / 512.0f);
  float var  = ss * (1.0f / 512.0f) - mean * mean;
  float sd = sqrtf(var + 1e-5f);
  if (tid == 0) { means[bm] = mean; stdev[bm] = sd; }
  float inv = 1.0f / sd;
  xr[(size_t)bm * 512 + tid]       = (v0 - mean) * inv;
  xr[(size_t)bm * 512 + tid + 256] = (v1 - mean) * inv;
}

// ---------------- decompose ----------------
__global__ __launch_bounds__(256) void decompose_kernel(const float* __restrict__ xr,
    float* __restrict__ dec) {
  int n = blockIdx.x, tid = threadIdx.x;
  __shared__ float xv[512];
  __shared__ float tr[512];
  __shared__ float sumS[24];
  for (int l = tid; l < 512; l += 256) xv[l] = xr[(size_t)n * 512 + l];
  if (tid < 24) sumS[tid] = 0.f;
  __syncthreads();
  for (int l = tid; l < 512; l += 256) {
    int t0 = l - 12; t0 = t0 < 0 ? 0 : (t0 > 488 ? 488 : t0);
    float s = 0.f;
    #pragma unroll
    for (int j = 0; j < 24; j++) s += xv[t0 + j];
    float t = s * (1.0f / 24.0f);
    tr[l] = t;
    atomicAdd(&sumS[l % 24], xv[l] - t);
  }
  __syncthreads();
  if (tid < 24) sumS[tid] *= (tid < 8) ? (1.0f / 22.0f) : (1.0f / 21.0f);
  __syncthreads();
  float* dp = dec + (size_t)n * 1536;
  for (int l = tid; l < 512; l += 256) {
    float t = tr[l], se = sumS[l % 24];
    dp[l] = t;
    dp[512 + l] = se;
    dp[1024 + l] = xv[l] - t - se;
  }
}

// ---------------- patch + embed -> h rows 4..67 (NO wpe yet) ----------------
__global__ __launch_bounds__(256) void embed_kernel(const float* __restrict__ dec,
    const float* __restrict__ in_w, const float* __restrict__ in_b, float* __restrict__ h) {
  int blk = blockIdx.x;            // 448 * 4
  int n = blk >> 2, pg = blk & 3;  // series, patch-group of 16
  int tid = threadIdx.x;
  __shared__ __align__(16) float tok[16][48];
  for (int idx = tid; idx < 768; idx += 256) {
    int p = idx / 48, k = idx - p * 48;
    int c = k >> 4, j = k & 15;
    int l = (pg * 16 + p) * 8 + j; if (l > 511) l = 511;
    tok[p][k] = dec[(size_t)n * 1536 + (size_t)c * 512 + l];
  }
  __syncthreads();
  const int d0 = tid, d1 = tid + 256, d2 = tid + 512;
  float acc[16][3];
  float b0 = in_b[d0], b1 = in_b[d1], b2 = in_b[d2];
  #pragma unroll
  for (int p = 0; p < 16; p++) { acc[p][0] = b0; acc[p][1] = b1; acc[p][2] = b2; }
  for (int kq = 0; kq < 12; kq++) {
    float w0[4], w1[4], w2[4];
    #pragma unroll
    for (int kk = 0; kk < 4; kk++) {
      const float* wp = in_w + (size_t)(kq * 4 + kk) * 768;
      w0[kk] = wp[d0]; w1[kk] = wp[d1]; w2[kk] = wp[d2];
    }
    #pragma unroll
    for (int p = 0; p < 16; p++) {
      float4 t = *(const float4*)&tok[p][kq * 4];
      acc[p][0] += t.x * w0[0]; acc[p][1] += t.x * w1[0]; acc[p][2] += t.x * w2[0];
      acc[p][0] += t.y * w0[1]; acc[p][1] += t.y * w1[1]; acc[p][2] += t.y * w2[1];
      acc[p][0] += t.z * w0[2]; acc[p][1] += t.z * w1[2]; acc[p][2] += t.z * w2[2];
      acc[p][0] += t.w * w0[3]; acc[p][1] += t.w * w1[3]; acc[p][2] += t.w * w2[3];
    }
  }
  #pragma unroll
  for (int p = 0; p < 16; p++) {
    float* outp = h + ((size_t)n * 68 + 4 + pg * 16 + p) * 768;
    outp[d0] = acc[p][0]; outp[d1] = acc[p][1]; outp[d2] = acc[p][2];
  }
}

// ---------------- key normalization ----------------
__global__ __launch_bounds__(256) void keyn_kernel(const float* __restrict__ pkey,
    float* __restrict__ keyn, double* __restrict__ kinv) {
  int k = blockIdx.x, tid = threadIdx.x;
  __shared__ double redd[4];
  float v[3];
  double ss = 0.0;
  #pragma unroll
  for (int i = 0; i < 3; i++) {
    v[i] = pkey[(size_t)k * 768 + tid + i * 256];
    ss += (double)v[i] * (double)v[i];
  }
  #pragma unroll
  for (int o = 32; o; o >>= 1) ss += __shfl_xor(ss, o, 64);
  int wid = tid >> 6, lane = tid & 63;
  if (lane == 0) redd[wid] = ss;
  __syncthreads();
  if (tid == 0) redd[0] = redd[0] + redd[1] + redd[2] + redd[3];
  __syncthreads();
  ss = redd[0];
  double inv = 1.0 / sqrt(ss > 1e-12 ? ss : 1e-12);
  #pragma unroll
  for (int i = 0; i < 3; i++)
    keyn[(size_t)k * 768 + tid + i * 256] = (float)((double)v[i] * inv);
  if (tid == 0) kinv[k] = inv;
}

// ---------------- xq ----------------
__global__ __launch_bounds__(256) void xq_kernel(const float* __restrict__ h,
    float* __restrict__ xq) {
  int n = blockIdx.x, tid = threadIdx.x;
  __shared__ float red[8];
  float vals[3];
  float ssl = 0.f;
  #pragma unroll
  for (int i = 0; i < 3; i++) {
    int d = tid + i * 256;
    const float* p = h + ((size_t)n * 68 + 4) * 768 + d;
    float s = 0.f;
    for (int pc = 0; pc < 64; pc++) s += p[(size_t)pc * 768];
    s *= (1.0f / 64.0f);
    vals[i] = s; ssl += s * s;
  }
  float ss = block_reduce_sum(ssl, red);
  float inv = rsqrtf(fmaxf(ss, 1e-12f));
  #pragma unroll
  for (int i = 0; i < 3; i++)
    xq[(size_t)n * 768 + tid + i * 256] = vals[i] * inv;
}

__global__ void zero_kernel(float* p) {
  if (threadIdx.x == 0 && blockIdx.x == 0) p[0] = 0.f;
}

// ---------------- sim matrix (f64, high-parallelism) ----------------
__global__ __launch_bounds__(256) void sim_kernel(
    const float* __restrict__ xq, const float* __restrict__ pkey,
    const double* __restrict__ kinv, double* __restrict__ simd) {
  int n = blockIdx.y;
  int kbase = blockIdx.x * 128;
  int tid = threadIdx.x;
  __shared__ __align__(16) float xqv[768];
  #pragma unroll
  for (int i = 0; i < 3; i++) xqv[tid + i * 256] = xq[(size_t)n * 768 + tid + i * 256];
  __syncthreads();
  int lane = tid & 63, wid = tid >> 6;
  double xd[12];
  #pragma unroll
  for (int i = 0; i < 12; i++) xd[i] = (double)xqv[lane * 12 + i];

  for (int k4 = kbase + wid * 4; k4 < kbase + 128; k4 += 16) {
    int kt[4];
    #pragma unroll
    for (int t = 0; t < 4; t++) { int k = k4 + t; kt[t] = k < 1000 ? k : 999; }
    float4 v[4][3];
    #pragma unroll
    for (int t = 0; t < 4; t++)
      #pragma unroll
      for (int j = 0; j < 3; j++)
        v[t][j] = *(const float4*)(pkey + (size_t)kt[t] * 768 + lane * 12 + j * 4);
    double a[4] = {0.0, 0.0, 0.0, 0.0};
    #pragma unroll
    for (int t = 0; t < 4; t++)
      #pragma unroll
      for (int j = 0; j < 3; j++) {
        a[t] += (double)v[t][j].x * xd[4 * j + 0];
        a[t] += (double)v[t][j].y * xd[4 * j + 1];
        a[t] += (double)v[t][j].z * xd[4 * j + 2];
        a[t] += (double)v[t][j].w * xd[4 * j + 3];
      }
    #pragma unroll
    for (int t = 0; t < 4; t++)
      #pragma unroll
      for (int o = 32; o; o >>= 1) a[t] += __shfl_xor(a[t], o, 64);
    if (lane == 0) {
      #pragma unroll
      for (int t = 0; t < 4; t++) {
        int k = k4 + t;
        if (k < 1000) simd[(size_t)n * 1000 + k] = a[t] * kinv[k];
      }
    }
  }
}

// ---------------- top-4 + prompt rows + reduce_sim ----------------
__global__ __launch_bounds__(256) void topk_kernel(
    const float* __restrict__ xq, const double* __restrict__ simd_g,
    const float* __restrict__ keyn, const float* __restrict__ wpe,
    float* __restrict__ h, float* __restrict__ rs_out) {
  int n = blockIdx.x, tid = threadIdx.x;
  __shared__ __align__(16) float xqv[768];
  __shared__ double simd_s[1000];
  __shared__ int idxs[4];
  __shared__ double redv[4];
  __shared__ int redi[4];
  __shared__ float red2[8];
  #pragma unroll
  for (int i = 0; i < 3; i++) xqv[tid + i * 256] = xq[(size_t)n * 768 + tid + i * 256];
  for (int k = tid; k < 1000; k += 256) simd_s[k] = simd_g[(size_t)n * 1000 + k];
  __syncthreads();
  int lane = tid & 63, wid = tid >> 6;
  for (int r = 0; r < 4; r++) {
    double bv = -1e300; int bi = 0x7fffffff;
    for (int k = tid; k < 1000; k += 256) {
      double v = simd_s[k];
      if (v > bv || (v == bv && k < bi)) { bv = v; bi = k; }
    }
    #pragma unroll
    for (int off = 32; off; off >>= 1) {
      double ov = __shfl_xor(bv, off, 64);
      int oi = __shfl_xor(bi, off, 64);
      if (ov > bv || (ov == bv && oi < bi)) { bv = ov; bi = oi; }
    }
    if (lane == 0) { redv[wid] = bv; redi[wid] = bi; }
    __syncthreads();
    if (tid == 0) {
      double fv = redv[0]; int fi = redi[0];
      for (int w = 1; w < 4; w++)
        if (redv[w] > fv || (redv[w] == fv && redi[w] < fi)) { fv = redv[w]; fi = redi[w]; }
      idxs[r] = fi; simd_s[fi] = -1e300;
    }
    __syncthreads();
  }
  float part = 0.f;
  for (int r = 0; r < 4; r++) {
    int ki = idxs[r];
    const float* kp = keyn + (size_t)ki * 768;
    const float* wp = wpe + (size_t)r * 768;
    float* hp = h + ((size_t)n * 68 + r) * 768;
    #pragma unroll
    for (int i = 0; i < 3; i++) {
      int d = tid + i * 256;
      float kv = kp[d];
      hp[d] = kv + wp[d];
      part += kv * xqv[d];
    }
  }
  part = block_reduce_sum(part, red2);
  if (tid == 0) atomicAdd(rs_out, part * (1.0f / 448.0f));
}

// ---------------- h rows 4..67 += wpe ----------------
__global__ __launch_bounds__(256) void addwpe_kernel(const float* __restrict__ wpe,
    float* __restrict__ h) {
  int np = blockIdx.x;
  int n = np >> 6, p = np & 63;
  int tid = threadIdx.x;
  const float* wp = wpe + (size_t)(4 + p) * 768;
  float* hp = h + ((size_t)n * 68 + 4 + p) * 768;
  #pragma unroll
  for (int i = 0; i < 3; i++) { int d = tid + i * 256; hp[d] += wp[d]; }
}

// ---------------- LayerNorm -> bf16 (wave-per-row, barrier-free) ----------------
// 4 rows/block (grid NTOK/4). Lane holds 12 consecutive f32 (3x float4);
// interleaved shfl_xor chain gives sum+sumsq; bf16 out as 8B stores.
__global__ __launch_bounds__(256) void ln_kernel(const float* __restrict__ src,
    ushort* __restrict__ dst, const float* __restrict__ g, const float* __restrict__ b) {
  int wid = threadIdx.x >> 6, lane = threadIdx.x & 63;
  size_t row = (size_t)blockIdx.x * 4 + wid;
  const float* xp = src + row * 768;
  ushort* yp = dst + row * 768;
  float4 v[3];
  float s = 0.f, ss = 0.f;
  #pragma unroll
  for (int j = 0; j < 3; j++) {
    v[j] = *(const float4*)(xp + lane * 4 + j * 256);
    s  += v[j].x + v[j].y + v[j].z + v[j].w;
    ss += v[j].x * v[j].x + v[j].y * v[j].y + v[j].z * v[j].z + v[j].w * v[j].w;
  }
  #pragma unroll
  for (int o = 32; o; o >>= 1) {
    s  += __shfl_xor(s, o, 64);
    ss += __shfl_xor(ss, o, 64);
  }
  float mean = s * (1.0f / 768.0f);
  float var  = ss * (1.0f / 768.0f) - mean * mean;
  float rs = rsqrtf(var + 1e-5f);
  #pragma unroll
  for (int j = 0; j < 3; j++) {
    int c = lane * 4 + j * 256;
    float4 gv = *(const float4*)(g + c);
    float4 bv = *(const float4*)(b + c);
    ushort o4[4];
    o4[0] = f2bf((v[j].x - mean) * rs * gv.x + bv.x);
    o4[1] = f2bf((v[j].y - mean) * rs * gv.y + bv.y);
    o4[2] = f2bf((v[j].z - mean) * rs * gv.z + bv.z);
    o4[3] = f2bf((v[j].w - mean) * rs * gv.w + bv.w);
    *(uint2*)(yp + c) = *(const uint2*)o4;
  }
}

// ---------------- cast+transpose weights: W[K][N] f32 -> WT[N][K] bf16 ----------------
__global__ __launch_bounds__(256) void tcast_kernel(const float* __restrict__ W,
    ushort* __restrict__ WT, int K, int N) {
  __shared__ ushort t[32][33];
  int n0 = blockIdx.x * 32, k0 = blockIdx.y * 32;
  int tx = threadIdx.x & 31, ty = threadIdx.x >> 5;   // 32 x 8
  #pragma unroll
  for (int i = 0; i < 4; i++) {
    int kk = ty + i * 8;
    t[kk][tx] = f2bf(W[(size_t)(k0 + kk) * N + n0 + tx]);
  }
  __syncthreads();
  #pragma unroll
  for (int i = 0; i < 4; i++) {
    int nn = ty + i * 8;
    WT[(size_t)(n0 + nn) * K + k0 + tx] = t[tx][nn];
  }
}

// ---------------- fused per-layer weight cast: 4 weights in one launch ----------
// flat grid 6912: [0,1728) qkv 768x2304, [1728,2304) aw 768x768,
// [2304,4608) fc 768x3072, [4608,6912) mp 3072x768. Same per-tile body as
// tcast_kernel (bit-identical outputs); branch is block-uniform.
__global__ __launch_bounds__(256) void tcast4_kernel(
    const float* __restrict__ qkv_w, const float* __restrict__ aw,
    const float* __restrict__ fc_w, const float* __restrict__ mp_w,
    ushort* __restrict__ wqT, ushort* __restrict__ waT,
    ushort* __restrict__ wfcT, ushort* __restrict__ wmpT) {
  int fid = blockIdx.x;
  const float* W; ushort* WT; int K, N, gx, rem;
  if (fid < 1728)      { W = qkv_w; WT = wqT;  K = 768;  N = 2304; gx = 72; rem = fid; }
  else if (fid < 2304) { W = aw;    WT = waT;  K = 768;  N = 768;  gx = 24; rem = fid - 1728; }
  else if (fid < 4608) { W = fc_w;  WT = wfcT; K = 768;  N = 3072; gx = 96; rem = fid - 2304; }
  else                 { W = mp_w;  WT = wmpT; K = 3072; N = 768;  gx = 24; rem = fid - 4608; }
  int n0 = (rem % gx) * 32, k0 = (rem / gx) * 32;
  __shared__ ushort t[32][33];
  int tx = threadIdx.x & 31, ty = threadIdx.x >> 5;   // 32 x 8
  #pragma unroll
  for (int i = 0; i < 4; i++) {
    int kk = ty + i * 8;
    t[kk][tx] = f2bf(W[(size_t)(k0 + kk) * N + n0 + tx]);
  }
  __syncthreads();
  #pragma unroll
  for (int i = 0; i < 4; i++) {
    int nn = ty + i * 8;
    WT[(size_t)(n0 + nn) * K + k0 + tx] = t[tx][nn];
  }
}

// ---------------- bf16 MFMA GEMM (m97-style global_load_lds staging) ----------------
// C = A(MxK) @ WT(NxK)^T + bias. 128x128 tile, 4 waves, 16x16x32 bf16.
// mode 0: C bf16;  1: C bf16 w/ gelu;  2: C fp32 += (residual)
__global__ __launch_bounds__(256) void mfma_gemm(const ushort* __restrict__ A,
    const ushort* __restrict__ WT, const float* __restrict__ bias, void* __restrict__ Cp,
    int M, int N, int K, int mode) {
  __shared__ ushort As[128 * 32];
  __shared__ ushort Bs[128 * 32];
  const int tid = threadIdx.x;
  const int row0 = blockIdx.y * 128, col0 = blockIdx.x * 128;
  const int w = tid >> 6, lane = tid & 63;
  const int wm = w >> 1, wn = w & 1;
  const int lm = lane & 15, quad = lane >> 4;
  const int srow = w * 16 + (lane >> 2);
  const int scol = (lane & 3) * 8;
  const ushort* agp0 = A  + (size_t)(row0 + srow)      * K + scol;
  const ushort* agp1 = A  + (size_t)(row0 + 64 + srow) * K + scol;
  const ushort* bgp0 = WT + (size_t)(col0 + srow)      * K + scol;
  const ushort* bgp1 = WT + (size_t)(col0 + 64 + srow) * K + scol;
  ushort* al0 = &As[w * 512];
  ushort* al1 = &As[2048 + w * 512];
  ushort* bl0 = &Bs[w * 512];
  ushort* bl1 = &Bs[2048 + w * 512];
  f32x4_t acc[4][4];
  #pragma unroll
  for (int mi = 0; mi < 4; mi++)
    #pragma unroll
    for (int ni = 0; ni < 4; ni++) acc[mi][ni] = (f32x4_t)(0.0f);

  for (int kb = 0; kb < K; kb += 32) {
    __syncthreads();
#ifdef HAS_GLL
    gll16(agp0 + kb, al0);
    gll16(agp1 + kb, al1);
    gll16(bgp0 + kb, bl0);
    gll16(bgp1 + kb, bl1);
#else
    {
      uint4 va0 = *(const uint4*)(agp0 + kb);
      uint4 va1 = *(const uint4*)(agp1 + kb);
      uint4 vb0 = *(const uint4*)(bgp0 + kb);
      uint4 vb1 = *(const uint4*)(bgp1 + kb);
      *(uint4*)&al0[lane * 8] = va0;
      *(uint4*)&al1[lane * 8] = va1;
      *(uint4*)&bl0[lane * 8] = vb0;
      *(uint4*)&bl1[lane * 8] = vb1;
    }
#endif
    __syncthreads();
    bf16x8_t af[4], bfr[4];
    #pragma unroll
    for (int mi = 0; mi < 4; mi++)
      af[mi] = *(const bf16x8_t*)&As[(wm * 64 + mi * 16 + lm) * 32 + quad * 8];
    #pragma unroll
    for (int ni = 0; ni < 4; ni++)
      bfr[ni] = *(const bf16x8_t*)&Bs[(wn * 64 + ni * 16 + lm) * 32 + quad * 8];
    #pragma unroll
    for (int mi = 0; mi < 4; mi++)
      #pragma unroll
      for (int ni = 0; ni < 4; ni++)
        acc[mi][ni] = __builtin_amdgcn_mfma_f32_16x16x32_bf16(af[mi], bfr[ni], acc[mi][ni], 0, 0, 0);
  }
  #pragma unroll
  for (int mi = 0; mi < 4; mi++) {
    #pragma unroll
    for (int ni = 0; ni < 4; ni++) {
      int gcol = col0 + wn * 64 + ni * 16 + lm;
      float bz = bias[gcol];
      #pragma unroll
      for (int r = 0; r < 4; r++) {
        int grow = row0 + wm * 64 + mi * 16 + quad * 4 + r;
        float v = acc[mi][ni][r] + bz;
        if (mode == 0)      ((ushort*)Cp)[(size_t)grow * N + gcol] = f2bf(v);
        else if (mode == 1) ((ushort*)Cp)[(size_t)grow * N + gcol] = f2bf(gelu_f(v));
        else { float* c = (float*)Cp + (size_t)grow * N + gcol; *c += v; }
      }
    }
  }
}

// ---------------- MFMA attention: block = (series-in-chunk, head) ----------------
__global__ __launch_bounds__(256) void attn_kernel(const ushort* __restrict__ qkvc,
    ushort* __restrict__ obase) {
  __shared__ __align__(16) ushort qk[2 * 80 * 64];
  __shared__ __align__(16) ushort vt[64][96];
  __shared__ __align__(16) float  sS[68][80];
  ushort* qs = qk;
  ushort* ks = qk + 80 * 64;
  ushort (*P)[96] = (ushort(*)[96])qk;

  int nh = blockIdx.x;
  int nl = nh / 12, hh = nh % 12;
  int tid = threadIdx.x;
  const int w = tid >> 6, lane = tid & 63;
  const int lm = lane & 15, quad = lane >> 4;
  const ushort* base = qkvc + (size_t)nl * 68 * 2304 + hh * 64;

  // vectorized load: one uint4 (8 bf16) per matrix per chunk; 68 rows x 8 segs
  for (int idx = tid; idx < 68 * 8; idx += 256) {
    int t = idx >> 3, seg = (idx & 7) * 8;
    const ushort* rp = base + (size_t)t * 2304 + seg;
    uint4 q = *(const uint4*)(rp);
    uint4 k = *(const uint4*)(rp + 768);
    uint4 v = *(const uint4*)(rp + 1536);
    *(uint4*)&qs[t * 64 + seg] = q;
    *(uint4*)&ks[t * 64 + seg] = k;
    const ushort* pv = (const ushort*)&v;
    #pragma unroll
    for (int j = 0; j < 8; j++) vt[seg + j][t] = pv[j];
  }
  for (int idx = tid; idx < 64 * 28; idx += 256) {
    int d = idx / 28, t = 68 + idx % 28;
    vt[d][t] = 0;
  }
  __syncthreads();

  for (int t5 = w; t5 < 25; t5 += 4) {
    int mi = t5 / 5, ni = t5 % 5;
    bf16x8_t a0 = *(const bf16x8_t*)&qs[(mi * 16 + lm) * 64 + quad * 8];
    bf16x8_t a1 = *(const bf16x8_t*)&qs[(mi * 16 + lm) * 64 + 32 + quad * 8];
    bf16x8_t b0 = *(const bf16x8_t*)&ks[(ni * 16 + lm) * 64 + quad * 8];
    bf16x8_t b1 = *(const bf16x8_t*)&ks[(ni * 16 + lm) * 64 + 32 + quad * 8];
    f32x4_t acc = (f32x4_t)(0.0f);
    acc = __builtin_amdgcn_mfma_f32_16x16x32_bf16(a0, b0, acc, 0, 0, 0);
    acc = __builtin_amdgcn_mfma_f32_16x16x32_bf16(a1, b1, acc, 0, 0, 0);
    int col = ni * 16 + lm;
    #pragma unroll
    for (int r = 0; r < 4; r++) {
      int row = mi * 16 + quad * 4 + r;
      if (row < 68) {
        float sv = (col > row || col >= 68) ? -1e9f : acc[r] * 0.125f;
        sS[row][col] = sv;
      }
    }
  }
  __syncthreads();

  // wave-parallel softmax: each 4-lane quad owns a row
  {
    int q = tid >> 2, lq = tid & 3;
    for (int r = q; r < 68; r += 64) {
      float mx = -1e30f;
      for (int c = lq; c < 80; c += 4) mx = fmaxf(mx, sS[r][c]);
      mx = fmaxf(mx, __shfl_xor(mx, 1, 64));
      mx = fmaxf(mx, __shfl_xor(mx, 2, 64));
      float s = 0.f;
      for (int c = lq; c < 80; c += 4) {
        float e = __expf(sS[r][c] - mx);
        sS[r][c] = e; s += e;
      }
      s += __shfl_xor(s, 1, 64);
      s += __shfl_xor(s, 2, 64);
      float inv = 1.0f / s;
      for (int c = lq; c < 80; c += 4) P[r][c] = f2bf(sS[r][c] * inv);
      for (int c = 80 + lq; c < 96; c += 4) P[r][c] = 0;
    }
    for (int idx = tid; idx < 12 * 96; idx += 256) {
      int r = 68 + idx / 96, c = idx % 96;
      P[r][c] = 0;
    }
  }
  __syncthreads();

  for (int t5 = w; t5 < 20; t5 += 4) {
    int mi = t5 % 5, ni = t5 / 5;
    f32x4_t acc = (f32x4_t)(0.0f);
    #pragma unroll
    for (int kk = 0; kk < 3; kk++) {
      bf16x8_t a = *(const bf16x8_t*)&P[mi * 16 + lm][kk * 32 + quad * 8];
      bf16x8_t b = *(const bf16x8_t*)&vt[ni * 16 + lm][kk * 32 + quad * 8];
      acc = __builtin_amdgcn_mfma_f32_16x16x32_bf16(a, b, acc, 0, 0, 0);
    }
    int col = ni * 16 + lm;
    #pragma unroll
    for (int r = 0; r < 4; r++) {
      int row = mi * 16 + quad * 4 + r;
      if (row < 68)
        obase[((size_t)nl * 68 + row) * 768 + hh * 64 + col] = f2bf(acc[r]);
    }
  }
}

// ---------------- final head ----------------
__global__ __launch_bounds__(256) void initof_kernel(const float* __restrict__ ob,
    float* __restrict__ of) {
  int i = blockIdx.x * 256 + threadIdx.x;
  of[i] = ob[i % 96];
}

// MFMA split-K head GEMM: of(1344x96) += A(1344x17408) @ WT(96x17408)^T
__global__ __launch_bounds__(256) void splitk_kernel(const ushort* __restrict__ A,
    const ushort* __restrict__ WT, float* __restrict__ of) {
  __shared__ ushort As[64 * 32];
  __shared__ ushort Ws[96 * 32];
  const int tid = threadIdx.x;
  const int row0 = blockIdx.x * 64;
  const int k0 = blockIdx.y * 1024;
  const int w = tid >> 6, lane = tid & 63;
  const int lm = lane & 15, quad = lane >> 4;
  const ushort* agp  = A  + (size_t)(row0 + (tid >> 2)) * 17408 + (tid & 3) * 8;
  const ushort* wgp1 = WT + (size_t)(tid >> 2) * 17408 + (tid & 3) * 8;
  const ushort* wgp2 = WT + (size_t)(64 + (tid >> 2)) * 17408 + (tid & 3) * 8;
  ushort* asl  = &As[w * 512];
  ushort* wsl1 = &Ws[w * 512];
  ushort* wsl2 = &Ws[2048 + w * 512];
  f32x4_t acc[6];
  #pragma unroll
  for (int ni = 0; ni < 6; ni++) acc[ni] = (f32x4_t)(0.0f);
  for (int kb = k0; kb < k0 + 1024; kb += 32) {
    __syncthreads();
#ifdef HAS_GLL
    gll16(agp + kb, asl);
    gll16(wgp1 + kb, wsl1);
    if (w < 2) gll16(wgp2 + kb, wsl2);
#else
    {
      uint4 va = *(const uint4*)(agp + kb);
      *(uint4*)&As[tid * 8] = va;
      uint4 vw = *(const uint4*)(wgp1 + kb);
      *(uint4*)&Ws[tid * 8] = vw;
      if (tid < 128) {
        uint4 vw2 = *(const uint4*)(wgp2 + kb);
        *(uint4*)&Ws[2048 + tid * 8] = vw2;
      }
    }
#endif
    __syncthreads();
    bf16x8_t af = *(const bf16x8_t*)&As[(w * 16 + lm) * 32 + quad * 8];
    #pragma unroll
    for (int ni = 0; ni < 6; ni++) {
      bf16x8_t bfrag = *(const bf16x8_t*)&Ws[(ni * 16 + lm) * 32 + quad * 8];
      acc[ni] = __builtin_amdgcn_mfma_f32_16x16x32_bf16(af, bfrag, acc[ni], 0, 0, 0);
    }
  }
  #pragma unroll
  for (int ni = 0; ni < 6; ni++) {
    int col = ni * 16 + lm;
    #pragma unroll
    for (int r = 0; r < 4; r++) {
      int grow = row0 + w * 16 + quad * 4 + r;
      atomicAdd(&of[(size_t)grow * 96 + col], acc[ni][r]);
    }
  }
}

__global__ void combine_kernel(const float* __restrict__ of, const float* __restrict__ stdev,
    const float* __restrict__ means, float* __restrict__ out) {
  int bm = blockIdx.x;
  int b = bm / 7, m = bm % 7;
  int j = threadIdx.x;
  if (j < 96) {
    float s = of[(size_t)(bm * 3 + 0) * 96 + j]
            + of[(size_t)(bm * 3 + 1) * 96 + j]
            + of[(size_t)(bm * 3 + 2) * 96 + j];
    out[(size_t)b * 672 + (size_t)j * 7 + m] = s * stdev[bm] + means[bm];
  }
}

// ---------------- launcher ----------------
extern "C" void kernel_launch(void* const* d_in, const int* in_sizes, int n_in,
                              void* d_out, int out_size, void* d_ws, size_t ws_size,
                              hipStream_t stream) {
  (void)in_sizes; (void)n_in; (void)out_size;
  const float* x     = (const float*)d_in[0];
  const float* in_w  = (const float*)d_in[2];
  const float* in_b  = (const float*)d_in[3];
  const float* pkey  = (const float*)d_in[4];
  const float* wpe   = (const float*)d_in[5];
  const float* ln1_g = (const float*)d_in[6];
  const float* ln1_b = (const float*)d_in[7];
  const float* qkv_w = (const float*)d_in[8];
  const float* qkv_b = (const float*)d_in[9];
  const float* aw    = (const float*)d_in[10];
  const float* ab    = (const float*)d_in[11];
  const float* ln2_g = (const float*)d_in[12];
  const float* ln2_b = (const float*)d_in[13];
  const float* fc_w  = (const float*)d_in[14];
  const float* fc_b  = (const float*)d_in[15];
  const float* mp_w  = (const float*)d_in[16];
  const float* mp_b  = (const float*)d_in[17];
  const float* lnf_g = (const float*)d_in[18];
  const float* lnf_b = (const float*)d_in[19];
  const float* out_w = (const float*)d_in[20];
  const float* out_b = (const float*)d_in[21];
  float* out = (float*)d_out;
  float* ws  = (float*)d_ws;

  // workspace layout: small (2,161,664 f) + h + abuf16 + w16 + scr (rest)
  float* means = ws;
  float* stdev = ws + 512;
  float* xr    = ws + 1024;
  float* dec   = xr + 229376;
  float* keyn  = dec + 688128;
  double* kinv = (double*)(keyn + 768000);
  float* xq    = keyn + 768000 + 2048;
  float* of    = xq + 344064;
  float* h     = of + 129024;                 // 23,396,352 f
  ushort* abuf16 = (ushort*)(h + 23396352);   // 23,396,352 us
  ushort* w16    = abuf16 + 23396352;         // 7,077,888 us
  ushort* scr16  = w16 + 7077888;             // remainder
  ushort* owT16  = scr16;                     // alias (only used after layers)

  // sim matrix (448 x 1000 f64 = 3.584 MB) reuses the xr+dec region
  // (3.67 MB, dead after embed_kernel; 8B-aligned: ws+4096 bytes)
  double* simd = (double*)xr;

  ushort* wqT  = w16;                         // 2304 x 768
  ushort* waT  = wqT + 2304 * 768;            // 768 x 768
  ushort* wfcT = waT + 768 * 768;             // 3072 x 768
  ushort* wmpT = wfcT + 3072 * 768;           // 768 x 3072

  // dynamic chunking from ws_size (constant across calls -> graph-safe)
  size_t scr_bytes = ws_size - (size_t)((char*)scr16 - (char*)ws);
  // qkv chunks: units of 17 tiles (= 2176 rows = 32 series), 14 units total
  long cap_qg = (long)(scr_bytes / (17ull * 128 * 2304 * 2));
  if (cap_qg > 14) cap_qg = 14;
  if (cap_qg < 1) cap_qg = 1;
  int nch_q = (int)((14 + cap_qg - 1) / cap_qg);
  int gpc = (14 + nch_q - 1) / nch_q;         // 17-tile groups per chunk
  // fc chunks: units of 1 tile (128 rows), 238 tiles total
  long cap_ft = (long)(scr_bytes / (128ull * 3072 * 2));
  if (cap_ft > 238) cap_ft = 238;
  if (cap_ft < 1) cap_ft = 1;
  int nch_f = (int)((238 + cap_ft - 1) / cap_ft);
  int tpc = (238 + nch_f - 1) / nch_f;        // tiles per chunk

  revin_kernel<<<448, 256, 0, stream>>>(x, xr, means, stdev);
  decompose_kernel<<<448, 256, 0, stream>>>(xr, dec);
  embed_kernel<<<1792, 256, 0, stream>>>(dec, in_w, in_b, h);
  keyn_kernel<<<1000, 256, 0, stream>>>(pkey, keyn, kinv);
  xq_kernel<<<448, 256, 0, stream>>>(h, xq);
  zero_kernel<<<1, 64, 0, stream>>>(out + 43008);
  sim_kernel<<<dim3(8, 448), 256, 0, stream>>>(xq, pkey, kinv, simd);
  topk_kernel<<<448, 256, 0, stream>>>(xq, simd, keyn, wpe, h, out + 43008);
  addwpe_kernel<<<NEMB, 256, 0, stream>>>(wpe, h);

  for (int l = 0; l < 6; l++) {
    tcast4_kernel<<<6912, 256, 0, stream>>>(
        qkv_w + (size_t)l * 768 * 2304, aw + (size_t)l * 768 * 768,
        fc_w + (size_t)l * 768 * 3072, mp_w + (size_t)l * 3072 * 768,
        wqT, waT, wfcT, wmpT);

    ln_kernel<<<NTOK / 4, 256, 0, stream>>>(h, abuf16, ln1_g + l * 768, ln1_b + l * 768);
    for (int g0 = 0; g0 < 14; ) {
      int g = (gpc < 14 - g0) ? gpc : (14 - g0);
      int tiles = g * 17, rows = g * 2176, series = g * 32;
      ushort* Ain = abuf16 + (size_t)g0 * 2176 * 768;
      mfma_gemm<<<dim3(18, tiles), 256, 0, stream>>>(
          Ain, wqT, qkv_b + l * 2304, scr16, rows, 2304, 768, 0);
      attn_kernel<<<series * 12, 256, 0, stream>>>(scr16, Ain);
      g0 += g;
    }
    mfma_gemm<<<dim3(6, 238), 256, 0, stream>>>(
        abuf16, waT, ab + l * 768, h, NTOK, 768, 768, 2);
    ln_kernel<<<NTOK / 4, 256, 0, stream>>>(h, abuf16, ln2_g + l * 768, ln2_b + l * 768);
    for (int t0 = 0; t0 < 238; ) {
      int t = (tpc < 238 - t0) ? tpc : (238 - t0);
      mfma_gemm<<<dim3(24, t), 256, 0, stream>>>(
          abuf16 + (size_t)t0 * 128 * 768, wfcT, fc_b + l * 3072, scr16,
          t * 128, 3072, 768, 1);
      mfma_gemm<<<dim3(6, t), 256, 0, stream>>>(
          scr16, wmpT, mp_b + l * 768, h + (size_t)t0 * 128 * 768,
          t * 128, 768, 3072, 2);
      t0 += t;
    }
  }
  ln_kernel<<<NTOK / 4, 256, 0, stream>>>(h, abuf16, lnf_g, lnf_b);
  tcast_kernel<<<dim3(3, 544), 256, 0, stream>>>(out_w, owT16, 17408, 96);
  initof_kernel<<<504, 256, 0, stream>>>(out_b, of);
  splitk_kernel<<<dim3(21, 17), 256, 0, stream>>>(abuf16, owT16, of);
  combine_kernel<<<448, 96, 0, stream>>>(of, stdev, means, out);
}

// Round 11
// 6204.144 us; speedup vs baseline: 1.0676x; 1.0316x over previous
//
#include <hip/hip_runtime.h>
#include <math.h>

// ---------------- constants ----------------
#define NTOK 30464    // 448*68 = 238 tiles of 128
#define NEMB 28672    // 448*64
typedef unsigned short ushort;
typedef __attribute__((ext_vector_type(8))) __bf16 bf16x8_t;
typedef __attribute__((ext_vector_type(4))) float f32x4_t;

#if defined(__has_builtin)
#if __has_builtin(__builtin_amdgcn_global_load_lds)
#define HAS_GLL 1
#endif
#endif

// ---------------- helpers ----------------
__device__ __forceinline__ ushort f2bf(float f) {
  unsigned int u = __float_as_uint(f);
  u += 0x7fffu + ((u >> 16) & 1u);   // RNE (finite inputs)
  return (ushort)(u >> 16);
}
__device__ __forceinline__ float bf2f(ushort u) {
  return __uint_as_float(((unsigned int)u) << 16);
}

#ifdef HAS_GLL
__device__ __forceinline__ void gll16(const ushort* g, ushort* l) {
  __builtin_amdgcn_global_load_lds(
      (const __attribute__((address_space(1))) unsigned int*)g,
      (__attribute__((address_space(3))) unsigned int*)l, 16, 0, 0);
}
#endif

__device__ __forceinline__ float block_reduce_sum(float v, float* scratch) {
  __syncthreads();
  #pragma unroll
  for (int o = 32; o; o >>= 1) v += __shfl_xor(v, o, 64);
  int wid = threadIdx.x >> 6, lane = threadIdx.x & 63;
  if (lane == 0) scratch[wid] = v;
  __syncthreads();
  if (threadIdx.x == 0) {
    float s = 0.f;
    int nw = (blockDim.x + 63) >> 6;
    for (int i = 0; i < nw; i++) s += scratch[i];
    scratch[0] = s;
  }
  __syncthreads();
  return scratch[0];
}

// exact tanh-gelu via sigmoid identity: 0.5x(1+tanh(z)) = x / (1 + e^{-2z})
__device__ __forceinline__ float gelu_f(float x) {
  float z2 = 1.5957691216057308f * (x + 0.044715f * x * x * x);
  return x / (1.0f + __expf(-z2));
}

// ---------------- RevIN ----------------
__global__ __launch_bounds__(256) void revin_kernel(const float* __restrict__ x,
    float* __restrict__ xr, float* __restrict__ means, float* __restrict__ stdev) {
  int bm = blockIdx.x;
  int b = bm / 7, m = bm % 7;
  int tid = threadIdx.x;
  __shared__ float red[8];
  float v0 = x[(size_t)b * 3584 + (size_t)tid * 7 + m];
  float v1 = x[(size_t)b * 3584 + (size_t)(tid + 256) * 7 + m];
  float s  = block_reduce_sum(v0 + v1, red);
  float ss = block_reduce_sum(v0 * v0 + v1 * v1, red);
  float mean = s * (1.0f / 512.0f);
  float var  = ss * (1.0f / 512.0f) - mean * mean;
  float sd = sqrtf(var + 1e-5f);
  if (tid == 0) { means[bm] = mean; stdev[bm] = sd; }
  float inv = 1.0f / sd;
  xr[(size_t)bm * 512 + tid]       = (v0 - mean) * inv;
  xr[(size_t)bm * 512 + tid + 256] = (v1 - mean) * inv;
}

// ---------------- decompose ----------------
__global__ __launch_bounds__(256) void decompose_kernel(const float* __restrict__ xr,
    float* __restrict__ dec) {
  int n = blockIdx.x, tid = threadIdx.x;
  __shared__ float xv[512];
  __shared__ float tr[512];
  __shared__ float sumS[24];
  for (int l = tid; l < 512; l += 256) xv[l] = xr[(size_t)n * 512 + l];
  if (tid < 24) sumS[tid] = 0.f;
  __syncthreads();
  for (int l = tid; l < 512; l += 256) {
    int t0 = l - 12; t0 = t0 < 0 ? 0 : (t0 > 488 ? 488 : t0);
    float s = 0.f;
    #pragma unroll
    for (int j = 0; j < 24; j++) s += xv[t0 + j];
    float t = s * (1.0f / 24.0f);
    tr[l] = t;
    atomicAdd(&sumS[l % 24], xv[l] - t);
  }
  __syncthreads();
  if (tid < 24) sumS[tid] *= (tid < 8) ? (1.0f / 22.0f) : (1.0f / 21.0f);
  __syncthreads();
  float* dp = dec + (size_t)n * 1536;
  for (int l = tid; l < 512; l += 256) {
    float t = tr[l], se = sumS[l % 24];
    dp[l] = t;
    dp[512 + l] = se;
    dp[1024 + l] = xv[l] - t - se;
  }
}

// ---------------- patch + embed -> h rows 4..67 (NO wpe yet) ----------------
__global__ __launch_bounds__(256) void embed_kernel(const float* __restrict__ dec,
    const float* __restrict__ in_w, const float* __restrict__ in_b, float* __restrict__ h) {
  int blk = blockIdx.x;            // 448 * 4
  int n = blk >> 2, pg = blk & 3;  // series, patch-group of 16
  int tid = threadIdx.x;
  __shared__ __align__(16) float tok[16][48];
  for (int idx = tid; idx < 768; idx += 256) {
    int p = idx / 48, k = idx - p * 48;
    int c = k >> 4, j = k & 15;
    int l = (pg * 16 + p) * 8 + j; if (l > 511) l = 511;
    tok[p][k] = dec[(size_t)n * 1536 + (size_t)c * 512 + l];
  }
  __syncthreads();
  const int d0 = tid, d1 = tid + 256, d2 = tid + 512;
  float acc[16][3];
  float b0 = in_b[d0], b1 = in_b[d1], b2 = in_b[d2];
  #pragma unroll
  for (int p = 0; p < 16; p++) { acc[p][0] = b0; acc[p][1] = b1; acc[p][2] = b2; }
  for (int kq = 0; kq < 12; kq++) {
    float w0[4], w1[4], w2[4];
    #pragma unroll
    for (int kk = 0; kk < 4; kk++) {
      const float* wp = in_w + (size_t)(kq * 4 + kk) * 768;
      w0[kk] = wp[d0]; w1[kk] = wp[d1]; w2[kk] = wp[d2];
    }
    #pragma unroll
    for (int p = 0; p < 16; p++) {
      float4 t = *(const float4*)&tok[p][kq * 4];
      acc[p][0] += t.x * w0[0]; acc[p][1] += t.x * w1[0]; acc[p][2] += t.x * w2[0];
      acc[p][0] += t.y * w0[1]; acc[p][1] += t.y * w1[1]; acc[p][2] += t.y * w2[1];
      acc[p][0] += t.z * w0[2]; acc[p][1] += t.z * w1[2]; acc[p][2] += t.z * w2[2];
      acc[p][0] += t.w * w0[3]; acc[p][1] += t.w * w1[3]; acc[p][2] += t.w * w2[3];
    }
  }
  #pragma unroll
  for (int p = 0; p < 16; p++) {
    float* outp = h + ((size_t)n * 68 + 4 + pg * 16 + p) * 768;
    outp[d0] = acc[p][0]; outp[d1] = acc[p][1]; outp[d2] = acc[p][2];
  }
}

// ---------------- key normalization ----------------
__global__ __launch_bounds__(256) void keyn_kernel(const float* __restrict__ pkey,
    float* __restrict__ keyn, double* __restrict__ kinv) {
  int k = blockIdx.x, tid = threadIdx.x;
  __shared__ double redd[4];
  float v[3];
  double ss = 0.0;
  #pragma unroll
  for (int i = 0; i < 3; i++) {
    v[i] = pkey[(size_t)k * 768 + tid + i * 256];
    ss += (double)v[i] * (double)v[i];
  }
  #pragma unroll
  for (int o = 32; o; o >>= 1) ss += __shfl_xor(ss, o, 64);
  int wid = tid >> 6, lane = tid & 63;
  if (lane == 0) redd[wid] = ss;
  __syncthreads();
  if (tid == 0) redd[0] = redd[0] + redd[1] + redd[2] + redd[3];
  __syncthreads();
  ss = redd[0];
  double inv = 1.0 / sqrt(ss > 1e-12 ? ss : 1e-12);
  #pragma unroll
  for (int i = 0; i < 3; i++)
    keyn[(size_t)k * 768 + tid + i * 256] = (float)((double)v[i] * inv);
  if (tid == 0) kinv[k] = inv;
}

// ---------------- xq ----------------
__global__ __launch_bounds__(256) void xq_kernel(const float* __restrict__ h,
    float* __restrict__ xq) {
  int n = blockIdx.x, tid = threadIdx.x;
  __shared__ float red[8];
  float vals[3];
  float ssl = 0.f;
  #pragma unroll
  for (int i = 0; i < 3; i++) {
    int d = tid + i * 256;
    const float* p = h + ((size_t)n * 68 + 4) * 768 + d;
    float s = 0.f;
    for (int pc = 0; pc < 64; pc++) s += p[(size_t)pc * 768];
    s *= (1.0f / 64.0f);
    vals[i] = s; ssl += s * s;
  }
  float ss = block_reduce_sum(ssl, red);
  float inv = rsqrtf(fmaxf(ss, 1e-12f));
  #pragma unroll
  for (int i = 0; i < 3; i++)
    xq[(size_t)n * 768 + tid + i * 256] = vals[i] * inv;
}

__global__ void zero_kernel(float* p) {
  if (threadIdx.x == 0 && blockIdx.x == 0) p[0] = 0.f;
}

// ---------------- sim matrix (f64, high-parallelism) ----------------
__global__ __launch_bounds__(256) void sim_kernel(
    const float* __restrict__ xq, const float* __restrict__ pkey,
    const double* __restrict__ kinv, double* __restrict__ simd) {
  int n = blockIdx.y;
  int kbase = blockIdx.x * 128;
  int tid = threadIdx.x;
  __shared__ __align__(16) float xqv[768];
  #pragma unroll
  for (int i = 0; i < 3; i++) xqv[tid + i * 256] = xq[(size_t)n * 768 + tid + i * 256];
  __syncthreads();
  int lane = tid & 63, wid = tid >> 6;
  double xd[12];
  #pragma unroll
  for (int i = 0; i < 12; i++) xd[i] = (double)xqv[lane * 12 + i];

  for (int k4 = kbase + wid * 4; k4 < kbase + 128; k4 += 16) {
    int kt[4];
    #pragma unroll
    for (int t = 0; t < 4; t++) { int k = k4 + t; kt[t] = k < 1000 ? k : 999; }
    float4 v[4][3];
    #pragma unroll
    for (int t = 0; t < 4; t++)
      #pragma unroll
      for (int j = 0; j < 3; j++)
        v[t][j] = *(const float4*)(pkey + (size_t)kt[t] * 768 + lane * 12 + j * 4);
    double a[4] = {0.0, 0.0, 0.0, 0.0};
    #pragma unroll
    for (int t = 0; t < 4; t++)
      #pragma unroll
      for (int j = 0; j < 3; j++) {
        a[t] += (double)v[t][j].x * xd[4 * j + 0];
        a[t] += (double)v[t][j].y * xd[4 * j + 1];
        a[t] += (double)v[t][j].z * xd[4 * j + 2];
        a[t] += (double)v[t][j].w * xd[4 * j + 3];
      }
    #pragma unroll
    for (int t = 0; t < 4; t++)
      #pragma unroll
      for (int o = 32; o; o >>= 1) a[t] += __shfl_xor(a[t], o, 64);
    if (lane == 0) {
      #pragma unroll
      for (int t = 0; t < 4; t++) {
        int k = k4 + t;
        if (k < 1000) simd[(size_t)n * 1000 + k] = a[t] * kinv[k];
      }
    }
  }
}

// ---------------- top-4 + prompt rows + reduce_sim ----------------
__global__ __launch_bounds__(256) void topk_kernel(
    const float* __restrict__ xq, const double* __restrict__ simd_g,
    const float* __restrict__ keyn, const float* __restrict__ wpe,
    float* __restrict__ h, float* __restrict__ rs_out) {
  int n = blockIdx.x, tid = threadIdx.x;
  __shared__ __align__(16) float xqv[768];
  __shared__ double simd_s[1000];
  __shared__ int idxs[4];
  __shared__ double redv[4];
  __shared__ int redi[4];
  __shared__ float red2[8];
  #pragma unroll
  for (int i = 0; i < 3; i++) xqv[tid + i * 256] = xq[(size_t)n * 768 + tid + i * 256];
  for (int k = tid; k < 1000; k += 256) simd_s[k] = simd_g[(size_t)n * 1000 + k];
  __syncthreads();
  int lane = tid & 63, wid = tid >> 6;
  for (int r = 0; r < 4; r++) {
    double bv = -1e300; int bi = 0x7fffffff;
    for (int k = tid; k < 1000; k += 256) {
      double v = simd_s[k];
      if (v > bv || (v == bv && k < bi)) { bv = v; bi = k; }
    }
    #pragma unroll
    for (int off = 32; off; off >>= 1) {
      double ov = __shfl_xor(bv, off, 64);
      int oi = __shfl_xor(bi, off, 64);
      if (ov > bv || (ov == bv && oi < bi)) { bv = ov; bi = oi; }
    }
    if (lane == 0) { redv[wid] = bv; redi[wid] = bi; }
    __syncthreads();
    if (tid == 0) {
      double fv = redv[0]; int fi = redi[0];
      for (int w = 1; w < 4; w++)
        if (redv[w] > fv || (redv[w] == fv && redi[w] < fi)) { fv = redv[w]; fi = redi[w]; }
      idxs[r] = fi; simd_s[fi] = -1e300;
    }
    __syncthreads();
  }
  float part = 0.f;
  for (int r = 0; r < 4; r++) {
    int ki = idxs[r];
    const float* kp = keyn + (size_t)ki * 768;
    const float* wp = wpe + (size_t)r * 768;
    float* hp = h + ((size_t)n * 68 + r) * 768;
    #pragma unroll
    for (int i = 0; i < 3; i++) {
      int d = tid + i * 256;
      float kv = kp[d];
      hp[d] = kv + wp[d];
      part += kv * xqv[d];
    }
  }
  part = block_reduce_sum(part, red2);
  if (tid == 0) atomicAdd(rs_out, part * (1.0f / 448.0f));
}

// ---------------- h rows 4..67 += wpe ----------------
__global__ __launch_bounds__(256) void addwpe_kernel(const float* __restrict__ wpe,
    float* __restrict__ h) {
  int np = blockIdx.x;
  int n = np >> 6, p = np & 63;
  int tid = threadIdx.x;
  const float* wp = wpe + (size_t)(4 + p) * 768;
  float* hp = h + ((size_t)n * 68 + 4 + p) * 768;
  #pragma unroll
  for (int i = 0; i < 3; i++) { int d = tid + i * 256; hp[d] += wp[d]; }
}

// ---------------- LayerNorm -> bf16 (wave-per-row, barrier-free) ----------------
__global__ __launch_bounds__(256) void ln_kernel(const float* __restrict__ src,
    ushort* __restrict__ dst, const float* __restrict__ g, const float* __restrict__ b) {
  int wid = threadIdx.x >> 6, lane = threadIdx.x & 63;
  size_t row = (size_t)blockIdx.x * 4 + wid;
  const float* xp = src + row * 768;
  ushort* yp = dst + row * 768;
  float4 v[3];
  float s = 0.f, ss = 0.f;
  #pragma unroll
  for (int j = 0; j < 3; j++) {
    v[j] = *(const float4*)(xp + lane * 4 + j * 256);
    s  += v[j].x + v[j].y + v[j].z + v[j].w;
    ss += v[j].x * v[j].x + v[j].y * v[j].y + v[j].z * v[j].z + v[j].w * v[j].w;
  }
  #pragma unroll
  for (int o = 32; o; o >>= 1) {
    s  += __shfl_xor(s, o, 64);
    ss += __shfl_xor(ss, o, 64);
  }
  float mean = s * (1.0f / 768.0f);
  float var  = ss * (1.0f / 768.0f) - mean * mean;
  float rs = rsqrtf(var + 1e-5f);
  #pragma unroll
  for (int j = 0; j < 3; j++) {
    int c = lane * 4 + j * 256;
    float4 gv = *(const float4*)(g + c);
    float4 bv = *(const float4*)(b + c);
    ushort o4[4];
    o4[0] = f2bf((v[j].x - mean) * rs * gv.x + bv.x);
    o4[1] = f2bf((v[j].y - mean) * rs * gv.y + bv.y);
    o4[2] = f2bf((v[j].z - mean) * rs * gv.z + bv.z);
    o4[3] = f2bf((v[j].w - mean) * rs * gv.w + bv.w);
    *(uint2*)(yp + c) = *(const uint2*)o4;
  }
}

// ---------------- cast+transpose weights: W[K][N] f32 -> WT[N][K] bf16 ----------------
__global__ __launch_bounds__(256) void tcast_kernel(const float* __restrict__ W,
    ushort* __restrict__ WT, int K, int N) {
  __shared__ ushort t[32][33];
  int n0 = blockIdx.x * 32, k0 = blockIdx.y * 32;
  int tx = threadIdx.x & 31, ty = threadIdx.x >> 5;   // 32 x 8
  #pragma unroll
  for (int i = 0; i < 4; i++) {
    int kk = ty + i * 8;
    t[kk][tx] = f2bf(W[(size_t)(k0 + kk) * N + n0 + tx]);
  }
  __syncthreads();
  #pragma unroll
  for (int i = 0; i < 4; i++) {
    int nn = ty + i * 8;
    WT[(size_t)(n0 + nn) * K + k0 + tx] = t[tx][nn];
  }
}

// ---------------- fused per-layer weight cast: 4 weights in one launch ----------
__global__ __launch_bounds__(256) void tcast4_kernel(
    const float* __restrict__ qkv_w, const float* __restrict__ aw,
    const float* __restrict__ fc_w, const float* __restrict__ mp_w,
    ushort* __restrict__ wqT, ushort* __restrict__ waT,
    ushort* __restrict__ wfcT, ushort* __restrict__ wmpT) {
  int fid = blockIdx.x;
  const float* W; ushort* WT; int K, N, gx, rem;
  if (fid < 1728)      { W = qkv_w; WT = wqT;  K = 768;  N = 2304; gx = 72; rem = fid; }
  else if (fid < 2304) { W = aw;    WT = waT;  K = 768;  N = 768;  gx = 24; rem = fid - 1728; }
  else if (fid < 4608) { W = fc_w;  WT = wfcT; K = 768;  N = 3072; gx = 96; rem = fid - 2304; }
  else                 { W = mp_w;  WT = wmpT; K = 3072; N = 768;  gx = 24; rem = fid - 4608; }
  int n0 = (rem % gx) * 32, k0 = (rem / gx) * 32;
  __shared__ ushort t[32][33];
  int tx = threadIdx.x & 31, ty = threadIdx.x >> 5;   // 32 x 8
  #pragma unroll
  for (int i = 0; i < 4; i++) {
    int kk = ty + i * 8;
    t[kk][tx] = f2bf(W[(size_t)(k0 + kk) * N + n0 + tx]);
  }
  __syncthreads();
  #pragma unroll
  for (int i = 0; i < 4; i++) {
    int nn = ty + i * 8;
    WT[(size_t)(n0 + nn) * K + k0 + tx] = t[tx][nn];
  }
}

// ---------------- bf16 MFMA GEMM (m97 staging, BK=64: 2 K-planes/barrier) -------
// C = A(MxK) @ WT(NxK)^T + bias. 128x128 tile, 4 waves, 16x16x32 bf16.
// LDS = two [128][32] planes per matrix (32 KB total). One barrier pair per
// 64-K (half the m97 barrier count); staging pattern, fragment layout, and
// accumulation order are identical to BK=32 -> bit-identical results.
// mode 0: C bf16;  1: C bf16 w/ gelu;  2: C fp32 += (residual)
__global__ __launch_bounds__(256) void mfma_gemm(const ushort* __restrict__ A,
    const ushort* __restrict__ WT, const float* __restrict__ bias, void* __restrict__ Cp,
    int M, int N, int K, int mode) {
  __shared__ ushort As[2 * 128 * 32];
  __shared__ ushort Bs[2 * 128 * 32];
  const int tid = threadIdx.x;
  const int row0 = blockIdx.y * 128, col0 = blockIdx.x * 128;
  const int w = tid >> 6, lane = tid & 63;
  const int wm = w >> 1, wn = w & 1;
  const int lm = lane & 15, quad = lane >> 4;
  const int srow = w * 16 + (lane >> 2);
  const int scol = (lane & 3) * 8;
  const ushort* agp0 = A  + (size_t)(row0 + srow)      * K + scol;
  const ushort* agp1 = A  + (size_t)(row0 + 64 + srow) * K + scol;
  const ushort* bgp0 = WT + (size_t)(col0 + srow)      * K + scol;
  const ushort* bgp1 = WT + (size_t)(col0 + 64 + srow) * K + scol;
  ushort* al0 = &As[w * 512];
  ushort* al1 = &As[2048 + w * 512];
  ushort* bl0 = &Bs[w * 512];
  ushort* bl1 = &Bs[2048 + w * 512];
  f32x4_t acc[4][4];
  #pragma unroll
  for (int mi = 0; mi < 4; mi++)
    #pragma unroll
    for (int ni = 0; ni < 4; ni++) acc[mi][ni] = (f32x4_t)(0.0f);

  for (int kb = 0; kb < K; kb += 64) {
    __syncthreads();
#ifdef HAS_GLL
    gll16(agp0 + kb, al0);
    gll16(agp1 + kb, al1);
    gll16(bgp0 + kb, bl0);
    gll16(bgp1 + kb, bl1);
    gll16(agp0 + kb + 32, al0 + 4096);
    gll16(agp1 + kb + 32, al1 + 4096);
    gll16(bgp0 + kb + 32, bl0 + 4096);
    gll16(bgp1 + kb + 32, bl1 + 4096);
#else
    {
      *(uint4*)&al0[lane * 8]        = *(const uint4*)(agp0 + kb);
      *(uint4*)&al1[lane * 8]        = *(const uint4*)(agp1 + kb);
      *(uint4*)&bl0[lane * 8]        = *(const uint4*)(bgp0 + kb);
      *(uint4*)&bl1[lane * 8]        = *(const uint4*)(bgp1 + kb);
      *(uint4*)&al0[4096 + lane * 8] = *(const uint4*)(agp0 + kb + 32);
      *(uint4*)&al1[4096 + lane * 8] = *(const uint4*)(agp1 + kb + 32);
      *(uint4*)&bl0[4096 + lane * 8] = *(const uint4*)(bgp0 + kb + 32);
      *(uint4*)&bl1[4096 + lane * 8] = *(const uint4*)(bgp1 + kb + 32);
    }
#endif
    __syncthreads();
    #pragma unroll
    for (int ks = 0; ks < 2; ks++) {
      bf16x8_t af[4], bfr[4];
      #pragma unroll
      for (int mi = 0; mi < 4; mi++)
        af[mi] = *(const bf16x8_t*)&As[ks * 4096 + (wm * 64 + mi * 16 + lm) * 32 + quad * 8];
      #pragma unroll
      for (int ni = 0; ni < 4; ni++)
        bfr[ni] = *(const bf16x8_t*)&Bs[ks * 4096 + (wn * 64 + ni * 16 + lm) * 32 + quad * 8];
      #pragma unroll
      for (int mi = 0; mi < 4; mi++)
        #pragma unroll
        for (int ni = 0; ni < 4; ni++)
          acc[mi][ni] = __builtin_amdgcn_mfma_f32_16x16x32_bf16(af[mi], bfr[ni], acc[mi][ni], 0, 0, 0);
    }
  }
  #pragma unroll
  for (int mi = 0; mi < 4; mi++) {
    #pragma unroll
    for (int ni = 0; ni < 4; ni++) {
      int gcol = col0 + wn * 64 + ni * 16 + lm;
      float bz = bias[gcol];
      #pragma unroll
      for (int r = 0; r < 4; r++) {
        int grow = row0 + wm * 64 + mi * 16 + quad * 4 + r;
        float v = acc[mi][ni][r] + bz;
        if (mode == 0)      ((ushort*)Cp)[(size_t)grow * N + gcol] = f2bf(v);
        else if (mode == 1) ((ushort*)Cp)[(size_t)grow * N + gcol] = f2bf(gelu_f(v));
        else { float* c = (float*)Cp + (size_t)grow * N + gcol; *c += v; }
      }
    }
  }
}

// ---------------- MFMA attention: block = (series-in-chunk, head) ----------------
__global__ __launch_bounds__(256) void attn_kernel(const ushort* __restrict__ qkvc,
    ushort* __restrict__ obase) {
  __shared__ __align__(16) ushort qk[2 * 80 * 64];
  __shared__ __align__(16) ushort vt[64][96];
  __shared__ __align__(16) float  sS[68][80];
  ushort* qs = qk;
  ushort* ks = qk + 80 * 64;
  ushort (*P)[96] = (ushort(*)[96])qk;

  int nh = blockIdx.x;
  int nl = nh / 12, hh = nh % 12;
  int tid = threadIdx.x;
  const int w = tid >> 6, lane = tid & 63;
  const int lm = lane & 15, quad = lane >> 4;
  const ushort* base = qkvc + (size_t)nl * 68 * 2304 + hh * 64;

  // vectorized load: one uint4 (8 bf16) per matrix per chunk; 68 rows x 8 segs
  for (int idx = tid; idx < 68 * 8; idx += 256) {
    int t = idx >> 3, seg = (idx & 7) * 8;
    const ushort* rp = base + (size_t)t * 2304 + seg;
    uint4 q = *(const uint4*)(rp);
    uint4 k = *(const uint4*)(rp + 768);
    uint4 v = *(const uint4*)(rp + 1536);
    *(uint4*)&qs[t * 64 + seg] = q;
    *(uint4*)&ks[t * 64 + seg] = k;
    const ushort* pv = (const ushort*)&v;
    #pragma unroll
    for (int j = 0; j < 8; j++) vt[seg + j][t] = pv[j];
  }
  for (int idx = tid; idx < 64 * 28; idx += 256) {
    int d = idx / 28, t = 68 + idx % 28;
    vt[d][t] = 0;
  }
  __syncthreads();

  for (int t5 = w; t5 < 25; t5 += 4) {
    int mi = t5 / 5, ni = t5 % 5;
    bf16x8_t a0 = *(const bf16x8_t*)&qs[(mi * 16 + lm) * 64 + quad * 8];
    bf16x8_t a1 = *(const bf16x8_t*)&qs[(mi * 16 + lm) * 64 + 32 + quad * 8];
    bf16x8_t b0 = *(const bf16x8_t*)&ks[(ni * 16 + lm) * 64 + quad * 8];
    bf16x8_t b1 = *(const bf16x8_t*)&ks[(ni * 16 + lm) * 64 + 32 + quad * 8];
    f32x4_t acc = (f32x4_t)(0.0f);
    acc = __builtin_amdgcn_mfma_f32_16x16x32_bf16(a0, b0, acc, 0, 0, 0);
    acc = __builtin_amdgcn_mfma_f32_16x16x32_bf16(a1, b1, acc, 0, 0, 0);
    int col = ni * 16 + lm;
    #pragma unroll
    for (int r = 0; r < 4; r++) {
      int row = mi * 16 + quad * 4 + r;
      if (row < 68) {
        float sv = (col > row || col >= 68) ? -1e9f : acc[r] * 0.125f;
        sS[row][col] = sv;
      }
    }
  }
  __syncthreads();

  // wave-parallel softmax: each 4-lane quad owns a row
  {
    int q = tid >> 2, lq = tid & 3;
    for (int r = q; r < 68; r += 64) {
      float mx = -1e30f;
      for (int c = lq; c < 80; c += 4) mx = fmaxf(mx, sS[r][c]);
      mx = fmaxf(mx, __shfl_xor(mx, 1, 64));
      mx = fmaxf(mx, __shfl_xor(mx, 2, 64));
      float s = 0.f;
      for (int c = lq; c < 80; c += 4) {
        float e = __expf(sS[r][c] - mx);
        sS[r][c] = e; s += e;
      }
      s += __shfl_xor(s, 1, 64);
      s += __shfl_xor(s, 2, 64);
      float inv = 1.0f / s;
      for (int c = lq; c < 80; c += 4) P[r][c] = f2bf(sS[r][c] * inv);
      for (int c = 80 + lq; c < 96; c += 4) P[r][c] = 0;
    }
    for (int idx = tid; idx < 12 * 96; idx += 256) {
      int r = 68 + idx / 96, c = idx % 96;
      P[r][c] = 0;
    }
  }
  __syncthreads();

  for (int t5 = w; t5 < 20; t5 += 4) {
    int mi = t5 % 5, ni = t5 / 5;
    f32x4_t acc = (f32x4_t)(0.0f);
    #pragma unroll
    for (int kk = 0; kk < 3; kk++) {
      bf16x8_t a = *(const bf16x8_t*)&P[mi * 16 + lm][kk * 32 + quad * 8];
      bf16x8_t b = *(const bf16x8_t*)&vt[ni * 16 + lm][kk * 32 + quad * 8];
      acc = __builtin_amdgcn_mfma_f32_16x16x32_bf16(a, b, acc, 0, 0, 0);
    }
    int col = ni * 16 + lm;
    #pragma unroll
    for (int r = 0; r < 4; r++) {
      int row = mi * 16 + quad * 4 + r;
      if (row < 68)
        obase[((size_t)nl * 68 + row) * 768 + hh * 64 + col] = f2bf(acc[r]);
    }
  }
}

// ---------------- final head ----------------
__global__ __launch_bounds__(256) void initof_kernel(const float* __restrict__ ob,
    float* __restrict__ of) {
  int i = blockIdx.x * 256 + threadIdx.x;
  of[i] = ob[i % 96];
}

// MFMA split-K head GEMM: of(1344x96) += A(1344x17408) @ WT(96x17408)^T
__global__ __launch_bounds__(256) void splitk_kernel(const ushort* __restrict__ A,
    const ushort* __restrict__ WT, float* __restrict__ of) {
  __shared__ ushort As[64 * 32];
  __shared__ ushort Ws[96 * 32];
  const int tid = threadIdx.x;
  const int row0 = blockIdx.x * 64;
  const int k0 = blockIdx.y * 1024;
  const int w = tid >> 6, lane = tid & 63;
  const int lm = lane & 15, quad = lane >> 4;
  const ushort* agp  = A  + (size_t)(row0 + (tid >> 2)) * 17408 + (tid & 3) * 8;
  const ushort* wgp1 = WT + (size_t)(tid >> 2) * 17408 + (tid & 3) * 8;
  const ushort* wgp2 = WT + (size_t)(64 + (tid >> 2)) * 17408 + (tid & 3) * 8;
  ushort* asl  = &As[w * 512];
  ushort* wsl1 = &Ws[w * 512];
  ushort* wsl2 = &Ws[2048 + w * 512];
  f32x4_t acc[6];
  #pragma unroll
  for (int ni = 0; ni < 6; ni++) acc[ni] = (f32x4_t)(0.0f);
  for (int kb = k0; kb < k0 + 1024; kb += 32) {
    __syncthreads();
#ifdef HAS_GLL
    gll16(agp + kb, asl);
    gll16(wgp1 + kb, wsl1);
    if (w < 2) gll16(wgp2 + kb, wsl2);
#else
    {
      uint4 va = *(const uint4*)(agp + kb);
      *(uint4*)&As[tid * 8] = va;
      uint4 vw = *(const uint4*)(wgp1 + kb);
      *(uint4*)&Ws[tid * 8] = vw;
      if (tid < 128) {
        uint4 vw2 = *(const uint4*)(wgp2 + kb);
        *(uint4*)&Ws[2048 + tid * 8] = vw2;
      }
    }
#endif
    __syncthreads();
    bf16x8_t af = *(const bf16x8_t*)&As[(w * 16 + lm) * 32 + quad * 8];
    #pragma unroll
    for (int ni = 0; ni < 6; ni++) {
      bf16x8_t bfrag = *(const bf16x8_t*)&Ws[(ni * 16 + lm) * 32 + quad * 8];
      acc[ni] = __builtin_amdgcn_mfma_f32_16x16x32_bf16(af, bfrag, acc[ni], 0, 0, 0);
    }
  }
  #pragma unroll
  for (int ni = 0; ni < 6; ni++) {
    int col = ni * 16 + lm;
    #pragma unroll
    for (int r = 0; r < 4; r++) {
      int grow = row0 + w * 16 + quad * 4 + r;
      atomicAdd(&of[(size_t)grow * 96 + col], acc[ni][r]);
    }
  }
}

__global__ void combine_kernel(const float* __restrict__ of, const float* __restrict__ stdev,
    const float* __restrict__ means, float* __restrict__ out) {
  int bm = blockIdx.x;
  int b = bm / 7, m = bm % 7;
  int j = threadIdx.x;
  if (j < 96) {
    float s = of[(size_t)(bm * 3 + 0) * 96 + j]
            + of[(size_t)(bm * 3 + 1) * 96 + j]
            + of[(size_t)(bm * 3 + 2) * 96 + j];
    out[(size_t)b * 672 + (size_t)j * 7 + m] = s * stdev[bm] + means[bm];
  }
}

// ---------------- launcher ----------------
extern "C" void kernel_launch(void* const* d_in, const int* in_sizes, int n_in,
                              void* d_out, int out_size, void* d_ws, size_t ws_size,
                              hipStream_t stream) {
  (void)in_sizes; (void)n_in; (void)out_size;
  const float* x     = (const float*)d_in[0];
  const float* in_w  = (const float*)d_in[2];
  const float* in_b  = (const float*)d_in[3];
  const float* pkey  = (const float*)d_in[4];
  const float* wpe   = (const float*)d_in[5];
  const float* ln1_g = (const float*)d_in[6];
  const float* ln1_b = (const float*)d_in[7];
  const float* qkv_w = (const float*)d_in[8];
  const float* qkv_b = (const float*)d_in[9];
  const float* aw    = (const float*)d_in[10];
  const float* ab    = (const float*)d_in[11];
  const float* ln2_g = (const float*)d_in[12];
  const float* ln2_b = (const float*)d_in[13];
  const float* fc_w  = (const float*)d_in[14];
  const float* fc_b  = (const float*)d_in[15];
  const float* mp_w  = (const float*)d_in[16];
  const float* mp_b  = (const float*)d_in[17];
  const float* lnf_g = (const float*)d_in[18];
  const float* lnf_b = (const float*)d_in[19];
  const float* out_w = (const float*)d_in[20];
  const float* out_b = (const float*)d_in[21];
  float* out = (float*)d_out;
  float* ws  = (float*)d_ws;

  // workspace layout: small (2,161,664 f) + h + abuf16 + w16 + scr (rest)
  float* means = ws;
  float* stdev = ws + 512;
  float* xr    = ws + 1024;
  float* dec   = xr + 229376;
  float* keyn  = dec + 688128;
  double* kinv = (double*)(keyn + 768000);
  float* xq    = keyn + 768000 + 2048;
  float* of    = xq + 344064;
  float* h     = of + 129024;                 // 23,396,352 f
  ushort* abuf16 = (ushort*)(h + 23396352);   // 23,396,352 us
  ushort* w16    = abuf16 + 23396352;         // 7,077,888 us
  ushort* scr16  = w16 + 7077888;             // remainder
  ushort* owT16  = scr16;                     // alias (only used after layers)

  // sim matrix (448 x 1000 f64 = 3.584 MB) reuses the xr+dec region
  // (3.67 MB, dead after embed_kernel; 8B-aligned: ws+4096 bytes)
  double* simd = (double*)xr;

  ushort* wqT  = w16;                         // 2304 x 768
  ushort* waT  = wqT + 2304 * 768;            // 768 x 768
  ushort* wfcT = waT + 768 * 768;             // 3072 x 768
  ushort* wmpT = wfcT + 3072 * 768;           // 768 x 3072

  // dynamic chunking from ws_size (constant across calls -> graph-safe)
  size_t scr_bytes = ws_size - (size_t)((char*)scr16 - (char*)ws);
  // qkv chunks: units of 17 tiles (= 2176 rows = 32 series), 14 units total
  long cap_qg = (long)(scr_bytes / (17ull * 128 * 2304 * 2));
  if (cap_qg > 14) cap_qg = 14;
  if (cap_qg < 1) cap_qg = 1;
  int nch_q = (int)((14 + cap_qg - 1) / cap_qg);
  int gpc = (14 + nch_q - 1) / nch_q;         // 17-tile groups per chunk
  // fc chunks: units of 1 tile (128 rows), 238 tiles total
  long cap_ft = (long)(scr_bytes / (128ull * 3072 * 2));
  if (cap_ft > 238) cap_ft = 238;
  if (cap_ft < 1) cap_ft = 1;
  int nch_f = (int)((238 + cap_ft - 1) / cap_ft);
  int tpc = (238 + nch_f - 1) / nch_f;        // tiles per chunk

  revin_kernel<<<448, 256, 0, stream>>>(x, xr, means, stdev);
  decompose_kernel<<<448, 256, 0, stream>>>(xr, dec);
  embed_kernel<<<1792, 256, 0, stream>>>(dec, in_w, in_b, h);
  keyn_kernel<<<1000, 256, 0, stream>>>(pkey, keyn, kinv);
  xq_kernel<<<448, 256, 0, stream>>>(h, xq);
  zero_kernel<<<1, 64, 0, stream>>>(out + 43008);
  sim_kernel<<<dim3(8, 448), 256, 0, stream>>>(xq, pkey, kinv, simd);
  topk_kernel<<<448, 256, 0, stream>>>(xq, simd, keyn, wpe, h, out + 43008);
  addwpe_kernel<<<NEMB, 256, 0, stream>>>(wpe, h);

  for (int l = 0; l < 6; l++) {
    tcast4_kernel<<<6912, 256, 0, stream>>>(
        qkv_w + (size_t)l * 768 * 2304, aw + (size_t)l * 768 * 768,
        fc_w + (size_t)l * 768 * 3072, mp_w + (size_t)l * 3072 * 768,
        wqT, waT, wfcT, wmpT);

    ln_kernel<<<NTOK / 4, 256, 0, stream>>>(h, abuf16, ln1_g + l * 768, ln1_b + l * 768);
    for (int g0 = 0; g0 < 14; ) {
      int g = (gpc < 14 - g0) ? gpc : (14 - g0);
      int tiles = g * 17, rows = g * 2176, series = g * 32;
      ushort* Ain = abuf16 + (size_t)g0 * 2176 * 768;
      mfma_gemm<<<dim3(18, tiles), 256, 0, stream>>>(
          Ain, wqT, qkv_b + l * 2304, scr16, rows, 2304, 768, 0);
      attn_kernel<<<series * 12, 256, 0, stream>>>(scr16, Ain);
      g0 += g;
    }
    mfma_gemm<<<dim3(6, 238), 256, 0, stream>>>(
        abuf16, waT, ab + l * 768, h, NTOK, 768, 768, 2);
    ln_kernel<<<NTOK / 4, 256, 0, stream>>>(h, abuf16, ln2_g + l * 768, ln2_b + l * 768);
    for (int t0 = 0; t0 < 238; ) {
      int t = (tpc < 238 - t0) ? tpc : (238 - t0);
      mfma_gemm<<<dim3(24, t), 256, 0, stream>>>(
          abuf16 + (size_t)t0 * 128 * 768, wfcT, fc_b + l * 3072, scr16,
          t * 128, 3072, 768, 1);
      mfma_gemm<<<dim3(6, t), 256, 0, stream>>>(
          scr16, wmpT, mp_b + l * 768, h + (size_t)t0 * 128 * 768,
          t * 128, 768, 3072, 2);
      t0 += t;
    }
  }
  ln_kernel<<<NTOK / 4, 256, 0, stream>>>(h, abuf16, lnf_g, lnf_b);
  tcast_kernel<<<dim3(3, 544), 256, 0, stream>>>(out_w, owT16, 17408, 96);
  initof_kernel<<<504, 256, 0, stream>>>(out_b, of);
  splitk_kernel<<<dim3(21, 17), 256, 0, stream>>>(abuf16, owT16, of);
  combine_kernel<<<448, 96, 0, stream>>>(of, stdev, means, out);
}